// Round 4
// baseline (493.991 us; speedup 1.0000x reference)
//
#include <hip/hip_runtime.h>
#include <math.h>

// KNN (weights='distance'): B=1024 queries, N=100000 train, D=64, K=16, 10 classes.
// Pipeline: K0 convert fp32->bf16 + norms | K1/K2 sample 2048 pts -> per-query
// threshold theta (16th smallest approx d2) | K3 MFMA + threshold filter ->
// candidate append (~780/query) | K4 exact fp32 rescore + lex top-16 + vote.

constexpr int D        = 64;
constexpr int K        = 16;
constexpr int NCLS     = 10;
constexpr int NCHUNK   = 96;     // filter chunks (grid.y)
constexpr int CHUNKLEN = 1056;   // multiple of 16; 96*1056 >= 100000, 100000%16==0
constexpr int NSUB     = 4;      // sample subchunks
constexpr int SUBLEN   = 512;    // 32 groups of 16
constexpr int CAP      = 4096;   // per-query candidate capacity

typedef __attribute__((ext_vector_type(8))) short bf16x8_t;
typedef __attribute__((ext_vector_type(4))) float f32x4_t;
typedef unsigned short ushort_t;

__device__ __forceinline__ ushort_t f32_to_bf16_rne(float f) {
  unsigned int u = __float_as_uint(f);
  unsigned int r = u + 0x7FFFu + ((u >> 16) & 1u);
  return (ushort_t)(r >> 16);
}

// ---- K0a: train fp32 -> bf16, plus fp32 row norms. 4 threads/row. ----
__global__ __launch_bounds__(256) void cvt_train(
    const float* __restrict__ t, ushort_t* __restrict__ tb,
    float* __restrict__ t2, int N)
{
  int gid = blockIdx.x * 256 + threadIdx.x;
  int row = gid >> 2, qt = gid & 3;
  if (row >= N) return;
  const float* src = t + (size_t)row * D + qt * 16;
  ushort_t*    dst = tb + (size_t)row * D + qt * 16;
  float nrm = 0.f;
  #pragma unroll
  for (int i = 0; i < 4; ++i) {
    float4 v = *reinterpret_cast<const float4*>(src + i * 4);
    nrm = fmaf(v.x, v.x, nrm); nrm = fmaf(v.y, v.y, nrm);
    nrm = fmaf(v.z, v.z, nrm); nrm = fmaf(v.w, v.w, nrm);
    uint2 hh = make_uint2(
      (unsigned)f32_to_bf16_rne(v.x) | ((unsigned)f32_to_bf16_rne(v.y) << 16),
      (unsigned)f32_to_bf16_rne(v.z) | ((unsigned)f32_to_bf16_rne(v.w) << 16));
    *reinterpret_cast<uint2*>(dst + i * 4) = hh;
  }
  nrm += __shfl_xor(nrm, 1);
  nrm += __shfl_xor(nrm, 2);
  if (qt == 0) t2[row] = nrm;
}

// ---- K0b: x fp32 -> bf16 (no norms needed; theta lives in t2-2c space). ----
__global__ __launch_bounds__(256) void cvt_x(
    const float* __restrict__ x, ushort_t* __restrict__ xb, int B)
{
  int gid = blockIdx.x * 256 + threadIdx.x;
  int row = gid >> 2, qt = gid & 3;
  if (row >= B) return;
  const float* src = x + (size_t)row * D + qt * 16;
  ushort_t*    dst = xb + (size_t)row * D + qt * 16;
  #pragma unroll
  for (int i = 0; i < 4; ++i) {
    float4 v = *reinterpret_cast<const float4*>(src + i * 4);
    uint2 hh = make_uint2(
      (unsigned)f32_to_bf16_rne(v.x) | ((unsigned)f32_to_bf16_rne(v.y) << 16),
      (unsigned)f32_to_bf16_rne(v.z) | ((unsigned)f32_to_bf16_rne(v.w) << 16));
    *reinterpret_cast<uint2*>(dst + i * 4) = hh;
  }
}

// ---- K1: sample pass. grid (B/64, NSUB). Per (query, subchunk): top-16 of
//      tmp = t2 - 2*dot over 512 sample points (union of 4 lane top-8s). ----
__global__ __launch_bounds__(256) void knn_sample(
    const ushort_t* __restrict__ tb, const ushort_t* __restrict__ xb,
    const float* __restrict__ t2, float* __restrict__ samp)
{
  __shared__ float md[256 * 8];
  const int tid = threadIdx.x;
  const int w = tid >> 6, lane = tid & 63;
  const int lh = lane & 15, lg = lane >> 4;
  const int qb = blockIdx.x, sub = blockIdx.y;
  const int q = qb * 64 + w * 16 + lh;

  // hoist B fragments (this lane's query row)
  const ushort_t* xr = xb + (size_t)q * D + lg * 8;
  bf16x8_t B0 = *reinterpret_cast<const bf16x8_t*>(xr);
  bf16x8_t B1 = *reinterpret_cast<const bf16x8_t*>(xr + 32);

  float Ld[8];
  #pragma unroll
  for (int e = 0; e < 8; ++e) Ld[e] = INFINITY;

  const int pstart = sub * SUBLEN;
  const ushort_t* aptr = tb + (size_t)pstart * D + lh * D + lg * 8;
  const float* t2p = t2 + pstart + lg * 4;

  for (int g = 0; g < SUBLEN / 16; ++g) {
    bf16x8_t a0 = *reinterpret_cast<const bf16x8_t*>(aptr);
    bf16x8_t a1 = *reinterpret_cast<const bf16x8_t*>(aptr + 32);
    float4 t2v = *reinterpret_cast<const float4*>(t2p);
    f32x4_t c = {0.f, 0.f, 0.f, 0.f};
    c = __builtin_amdgcn_mfma_f32_16x16x32_bf16(a0, B0, c, 0, 0, 0);
    c = __builtin_amdgcn_mfma_f32_16x16x32_bf16(a1, B1, c, 0, 0, 0);
    float tmp0 = fmaf(-2.f, c[0], t2v.x);
    float tmp1 = fmaf(-2.f, c[1], t2v.y);
    float tmp2 = fmaf(-2.f, c[2], t2v.z);
    float tmp3 = fmaf(-2.f, c[3], t2v.w);
    #pragma unroll
    for (int r = 0; r < 4; ++r) {
      float tv = (r == 0) ? tmp0 : (r == 1) ? tmp1 : (r == 2) ? tmp2 : tmp3;
      if (tv < Ld[7]) {
        Ld[7] = tv;
        #pragma unroll
        for (int e = 7; e > 0; --e)
          if (Ld[e] < Ld[e - 1]) { float s = Ld[e]; Ld[e] = Ld[e - 1]; Ld[e - 1] = s; }
      }
    }
    aptr += 16 * D; t2p += 16;
  }

  #pragma unroll
  for (int e = 0; e < 8; ++e) md[tid * 8 + e] = Ld[e];
  __syncthreads();

  if (tid < 64) {
    const int w2 = tid >> 4, lh2 = tid & 15;
    const int b0 = (w2 * 64 + 0 * 16 + lh2) * 8;
    const int b1 = (w2 * 64 + 1 * 16 + lh2) * 8;
    const int b2 = (w2 * 64 + 2 * 16 + lh2) * 8;
    const int b3 = (w2 * 64 + 3 * 16 + lh2) * 8;
    int h0 = 0, h1 = 0, h2 = 0, h3 = 0;
    float* outp = samp + ((size_t)(qb * 64 + tid)) * (NSUB * 16) + sub * 16;
    for (int r = 0; r < 16; ++r) {
      float d0 = (h0 < 8) ? md[b0 + h0] : INFINITY;
      float d1 = (h1 < 8) ? md[b1 + h1] : INFINITY;
      float d2 = (h2 < 8) ? md[b2 + h2] : INFINITY;
      float d3 = (h3 < 8) ? md[b3 + h3] : INFINITY;
      float bd = d0; int bt = 0;
      if (d1 < bd) { bd = d1; bt = 1; }
      if (d2 < bd) { bd = d2; bt = 2; }
      if (d3 < bd) { bd = d3; bt = 3; }
      if (bt == 0) h0++; else if (bt == 1) h1++; else if (bt == 2) h2++; else h3++;
      outp[r] = bd;
    }
  }
}

// ---- K2: theta[q] = 16th smallest of the 4 merged sorted-16 lists; cnt=0. ----
__global__ __launch_bounds__(256) void reduce_theta(
    const float* __restrict__ samp, float* __restrict__ theta,
    int* __restrict__ cnt, int B)
{
  int q = blockIdx.x * 256 + threadIdx.x;
  if (q >= B) return;
  const float* s = samp + (size_t)q * (NSUB * 16);
  int h0 = 0, h1 = 0, h2 = 0, h3 = 0;
  float bd = INFINITY;
  for (int r = 0; r < 16; ++r) {
    float d0 = (h0 < 16) ? s[0 * 16 + h0] : INFINITY;
    float d1 = (h1 < 16) ? s[1 * 16 + h1] : INFINITY;
    float d2 = (h2 < 16) ? s[2 * 16 + h2] : INFINITY;
    float d3 = (h3 < 16) ? s[3 * 16 + h3] : INFINITY;
    bd = d0; int bt = 0;
    if (d1 < bd) { bd = d1; bt = 1; }
    if (d2 < bd) { bd = d2; bt = 2; }
    if (d3 < bd) { bd = d3; bt = 3; }
    if (bt == 0) h0++; else if (bt == 1) h1++; else if (bt == 2) h2++; else h3++;
  }
  theta[q] = bd;   // sample-16th in (t2 - 2c) space
  cnt[q] = 0;
}

// ---- K3: main filter. grid (B/64, NCHUNK), 4 waves x 16 queries. No LDS,
//      no barriers: MFMA -> fma+cmp vs theta -> rare atomic append. ----
__global__ __launch_bounds__(256) void knn_filter(
    const ushort_t* __restrict__ tb, const ushort_t* __restrict__ xb,
    const float* __restrict__ t2, const float* __restrict__ theta,
    int* __restrict__ cnt, int* __restrict__ cand, int N)
{
  const int tid = threadIdx.x;
  const int w = tid >> 6, lane = tid & 63;
  const int lh = lane & 15, lg = lane >> 4;
  const int qb = blockIdx.x, ch = blockIdx.y;
  const int q = qb * 64 + w * 16 + lh;

  const int g0 = ch * CHUNKLEN;
  int navail = N - g0;
  if (navail <= 0) return;
  const int ngroups = (navail < CHUNKLEN ? navail : CHUNKLEN) >> 4;

  const ushort_t* xr = xb + (size_t)q * D + lg * 8;
  bf16x8_t B0 = *reinterpret_cast<const bf16x8_t*>(xr);
  bf16x8_t B1 = *reinterpret_cast<const bf16x8_t*>(xr + 32);
  const float th = theta[q];

  const ushort_t* aptr = tb + (size_t)g0 * D + lh * D + lg * 8;
  const float* t2p = t2 + g0 + lg * 4;
  int pbase = g0 + lg * 4;
  int* mycand = cand + (size_t)q * CAP;

  for (int g = 0; g < ngroups; ++g) {
    bf16x8_t a0 = *reinterpret_cast<const bf16x8_t*>(aptr);
    bf16x8_t a1 = *reinterpret_cast<const bf16x8_t*>(aptr + 32);
    float4 t2v = *reinterpret_cast<const float4*>(t2p);
    f32x4_t c = {0.f, 0.f, 0.f, 0.f};
    c = __builtin_amdgcn_mfma_f32_16x16x32_bf16(a0, B0, c, 0, 0, 0);
    c = __builtin_amdgcn_mfma_f32_16x16x32_bf16(a1, B1, c, 0, 0, 0);
    float tmp0 = fmaf(-2.f, c[0], t2v.x);
    float tmp1 = fmaf(-2.f, c[1], t2v.y);
    float tmp2 = fmaf(-2.f, c[2], t2v.z);
    float tmp3 = fmaf(-2.f, c[3], t2v.w);
    if (tmp0 <= th) { int p = atomicAdd(cnt + q, 1); if (p < CAP) mycand[p] = pbase + 0; }
    if (tmp1 <= th) { int p = atomicAdd(cnt + q, 1); if (p < CAP) mycand[p] = pbase + 1; }
    if (tmp2 <= th) { int p = atomicAdd(cnt + q, 1); if (p < CAP) mycand[p] = pbase + 2; }
    if (tmp3 <= th) { int p = atomicAdd(cnt + q, 1); if (p < CAP) mycand[p] = pbase + 3; }
    aptr += 16 * D; t2p += 16; pbase += 16;
  }
}

// ---- K4: exact rescore + lex top-16 + weighted vote. 4 queries/block. ----
__global__ __launch_bounds__(256) void knn_vote(
    const float* __restrict__ x, const float* __restrict__ train,
    const float* __restrict__ t2, const int* __restrict__ labels,
    const int* __restrict__ cnt, const int* __restrict__ cand,
    float* __restrict__ out, int B, int N)
{
  const int w = threadIdx.x >> 6, lane = threadIdx.x & 63;
  const int q = blockIdx.x * 4 + w;
  if (q >= B) return;

  // query row in registers (identical across lanes -> L1 broadcast)
  const float* xr = x + (size_t)q * D;
  float4 xv[16];
  #pragma unroll
  for (int i = 0; i < 16; ++i) xv[i] = *reinterpret_cast<const float4*>(xr + i * 4);
  float x2 = 0.f;
  #pragma unroll
  for (int i = 0; i < 16; ++i) {
    x2 = fmaf(xv[i].x, xv[i].x, x2); x2 = fmaf(xv[i].y, xv[i].y, x2);
    x2 = fmaf(xv[i].z, xv[i].z, x2); x2 = fmaf(xv[i].w, xv[i].w, x2);
  }

  int n = cnt[q]; if (n > CAP) n = CAP;

  float Ld[K]; int Li[K];
  #pragma unroll
  for (int e = 0; e < K; ++e) { Ld[e] = INFINITY; Li[e] = 0x7fffffff; }

  for (int j = lane; j < n; j += 64) {
    int idx = cand[(size_t)q * CAP + j];
    const float* tr = train + (size_t)idx * D;
    float dot = 0.f;
    #pragma unroll
    for (int i = 0; i < 16; ++i) {
      float4 tv = *reinterpret_cast<const float4*>(tr + i * 4);
      dot = fmaf(xv[i].x, tv.x, dot); dot = fmaf(xv[i].y, tv.y, dot);
      dot = fmaf(xv[i].z, tv.z, dot); dot = fmaf(xv[i].w, tv.w, dot);
    }
    float d2 = fmaxf(x2 - 2.f * dot + t2[idx], 0.f);
    // (d2, idx) lexicographic insert -> deterministic despite append order
    if (d2 < Ld[K - 1] || (d2 == Ld[K - 1] && idx < Li[K - 1])) {
      Ld[K - 1] = d2; Li[K - 1] = idx;
      #pragma unroll
      for (int e = K - 1; e > 0; --e) {
        bool sw = (Ld[e] < Ld[e - 1]) || (Ld[e] == Ld[e - 1] && Li[e] < Li[e - 1]);
        if (sw) {
          float td = Ld[e]; Ld[e] = Ld[e - 1]; Ld[e - 1] = td;
          int   ti = Li[e]; Li[e] = Li[e - 1]; Li[e - 1] = ti;
        }
      }
    }
  }

  float accw[NCLS]; float acci[NCLS];
  #pragma unroll
  for (int c = 0; c < NCLS; ++c) { accw[c] = 0.f; acci[c] = 0.f; }
  int anyInf = 0;

  for (int r = 0; r < K; ++r) {
    float bd = Ld[0]; int bi = Li[0];
    #pragma unroll
    for (int s = 0; s < 6; ++s) {
      int off = 32 >> s;
      float od = __shfl_xor(bd, off);
      int   oi = __shfl_xor(bi, off);
      if (od < bd || (od == bd && oi < bi)) { bd = od; bi = oi; }
    }
    if (Ld[0] == bd && Li[0] == bi) {   // pop winner (idx unique -> one lane)
      #pragma unroll
      for (int e = 0; e < K - 1; ++e) { Ld[e] = Ld[e + 1]; Li[e] = Li[e + 1]; }
      Ld[K - 1] = INFINITY; Li[K - 1] = 0x7fffffff;
    }
    if (bd < INFINITY) {
      float dist = sqrtf(bd);
      int lab = labels[bi < N ? bi : 0];
      int isz = (dist == 0.f) ? 1 : 0;
      anyInf |= isz;
      float wgt = 1.f / dist;
      #pragma unroll
      for (int c = 0; c < NCLS; ++c) {
        accw[c] += (lab == c) ? wgt : 0.f;
        acci[c] += (lab == c && isz) ? 1.f : 0.f;
      }
    }
  }

  if (lane == 0) {
    float proba[NCLS]; float s = 0.f;
    #pragma unroll
    for (int c = 0; c < NCLS; ++c) { proba[c] = anyInf ? acci[c] : accw[c]; s += proba[c]; }
    if (s == 0.f) s = 1.f;
    #pragma unroll
    for (int c = 0; c < NCLS; ++c) proba[c] = proba[c] / s;
    int best = 0; float bv = proba[0];
    #pragma unroll
    for (int c = 1; c < NCLS; ++c) if (proba[c] > bv) { bv = proba[c]; best = c; }
    out[q] = (float)best;
    #pragma unroll
    for (int c = 0; c < NCLS; ++c) out[B + q * NCLS + c] = proba[c];
  }
}

extern "C" void kernel_launch(void* const* d_in, const int* in_sizes, int n_in,
                              void* d_out, int out_size, void* d_ws, size_t ws_size,
                              hipStream_t stream)
{
  const float* x      = (const float*)d_in[0];
  const float* train  = (const float*)d_in[1];
  const int*   labels = (const int*)d_in[2];
  float* out = (float*)d_out;

  const int B = in_sizes[0] / D;   // 1024
  const int N = in_sizes[2];       // 100000

  // workspace carve (all offsets 16B-aligned)
  char* ws = (char*)d_ws;
  size_t off = 0;
  ushort_t* train_bf = (ushort_t*)(ws + off); off += (size_t)N * D * 2;          // 12.8 MB
  ushort_t* x_bf     = (ushort_t*)(ws + off); off += (size_t)B * D * 2;          // 128 KB
  float*    t2       = (float*)(ws + off);    off += (size_t)N * 4;              // 400 KB
  float*    samp     = (float*)(ws + off);    off += (size_t)B * NSUB * 16 * 4;  // 256 KB
  float*    theta    = (float*)(ws + off);    off += (size_t)B * 4;
  int*      cnt      = (int*)(ws + off);      off += (size_t)B * 4;
  int*      cand     = (int*)(ws + off);      off += (size_t)B * CAP * 4;        // 16.8 MB

  cvt_train<<<(N * 4 + 255) / 256, 256, 0, stream>>>(train, train_bf, t2, N);
  cvt_x<<<(B * 4 + 255) / 256, 256, 0, stream>>>(x, x_bf, B);
  knn_sample<<<dim3(B / 64, NSUB), 256, 0, stream>>>(train_bf, x_bf, t2, samp);
  reduce_theta<<<(B + 255) / 256, 256, 0, stream>>>(samp, theta, cnt, B);
  knn_filter<<<dim3(B / 64, NCHUNK), 256, 0, stream>>>(train_bf, x_bf, t2, theta, cnt, cand, N);
  knn_vote<<<(B + 3) / 4, 256, 0, stream>>>(x, train, t2, labels, cnt, cand, out, B, N);
}

// Round 5
// 370.688 us; speedup vs baseline: 1.3326x; 1.3326x over previous
//
#include <hip/hip_runtime.h>
#include <math.h>

// KNN (weights='distance'): B=1024 queries, N=100000 train, D=64, K=16, 10 classes.
// Pipeline: K0 fp32->bf16 + norms | K1 sample 8192 pts (per-lane top-8) |
// K2 wave-merge -> theta[q] (sample 16th smallest in t2-2c space) |
// K3 MFMA filter -> per-(q,chunk) fixed-slot lists via LDS (no global atomics) |
// K4 exact fp32 rescore + lex top-16 + weighted vote.

constexpr int D        = 64;
constexpr int K        = 16;
constexpr int NCLS     = 10;
constexpr int CHUNKLEN = 1024;   // points per filter chunk (64 groups of 16)
constexpr int NCHUNK   = 98;     // 98*1024 = 100352 >= 100000
constexpr int NSUB     = 16;     // sample subchunks
constexpr int SUBLEN   = 512;    // sample points per subchunk (8192 total)
constexpr int SLOT     = 32;     // candidate slots per (query, chunk); avg fill ~2

typedef __attribute__((ext_vector_type(8))) short bf16x8_t;
typedef __attribute__((ext_vector_type(4))) float f32x4_t;
typedef unsigned short ushort_t;

__device__ __forceinline__ ushort_t f32_to_bf16_rne(float f) {
  unsigned int u = __float_as_uint(f);
  unsigned int r = u + 0x7FFFu + ((u >> 16) & 1u);
  return (ushort_t)(r >> 16);
}

// ---- K0a: train fp32 -> bf16, plus fp32 row norms. 4 threads/row. ----
__global__ __launch_bounds__(256) void cvt_train(
    const float* __restrict__ t, ushort_t* __restrict__ tb,
    float* __restrict__ t2, int N)
{
  int gid = blockIdx.x * 256 + threadIdx.x;
  int row = gid >> 2, qt = gid & 3;
  if (row >= N) return;
  const float* src = t + (size_t)row * D + qt * 16;
  ushort_t*    dst = tb + (size_t)row * D + qt * 16;
  float nrm = 0.f;
  #pragma unroll
  for (int i = 0; i < 4; ++i) {
    float4 v = *reinterpret_cast<const float4*>(src + i * 4);
    nrm = fmaf(v.x, v.x, nrm); nrm = fmaf(v.y, v.y, nrm);
    nrm = fmaf(v.z, v.z, nrm); nrm = fmaf(v.w, v.w, nrm);
    uint2 hh = make_uint2(
      (unsigned)f32_to_bf16_rne(v.x) | ((unsigned)f32_to_bf16_rne(v.y) << 16),
      (unsigned)f32_to_bf16_rne(v.z) | ((unsigned)f32_to_bf16_rne(v.w) << 16));
    *reinterpret_cast<uint2*>(dst + i * 4) = hh;
  }
  nrm += __shfl_xor(nrm, 1);
  nrm += __shfl_xor(nrm, 2);
  if (qt == 0) t2[row] = nrm;
}

// ---- K0b: x fp32 -> bf16. ----
__global__ __launch_bounds__(256) void cvt_x(
    const float* __restrict__ x, ushort_t* __restrict__ xb, int B)
{
  int gid = blockIdx.x * 256 + threadIdx.x;
  int row = gid >> 2, qt = gid & 3;
  if (row >= B) return;
  const float* src = x + (size_t)row * D + qt * 16;
  ushort_t*    dst = xb + (size_t)row * D + qt * 16;
  #pragma unroll
  for (int i = 0; i < 4; ++i) {
    float4 v = *reinterpret_cast<const float4*>(src + i * 4);
    uint2 hh = make_uint2(
      (unsigned)f32_to_bf16_rne(v.x) | ((unsigned)f32_to_bf16_rne(v.y) << 16),
      (unsigned)f32_to_bf16_rne(v.z) | ((unsigned)f32_to_bf16_rne(v.w) << 16));
    *reinterpret_cast<uint2*>(dst + i * 4) = hh;
  }
}

// ---- K1: sample pass. grid (B/64, NSUB). Lane keeps top-8 (sorted) of its
//      128 sample points in tmp = t2 - 2*dot space; writes raw 8 values.
//      (Dropping a lane's 9th+ value only raises theta -> still safe.) ----
__global__ __launch_bounds__(256) void knn_sample(
    const ushort_t* __restrict__ tb, const ushort_t* __restrict__ xb,
    const float* __restrict__ t2, float* __restrict__ samp)
{
  const int tid = threadIdx.x;
  const int w = tid >> 6, lane = tid & 63;
  const int lh = lane & 15, lg = lane >> 4;
  const int qb = blockIdx.x, sub = blockIdx.y;
  const int q = qb * 64 + w * 16 + lh;

  const ushort_t* xr = xb + (size_t)q * D + lg * 8;
  bf16x8_t B0 = *reinterpret_cast<const bf16x8_t*>(xr);
  bf16x8_t B1 = *reinterpret_cast<const bf16x8_t*>(xr + 32);

  float Ld[8];
  #pragma unroll
  for (int e = 0; e < 8; ++e) Ld[e] = INFINITY;

  const int pstart = sub * SUBLEN;
  const ushort_t* aptr = tb + (size_t)pstart * D + lh * D + lg * 8;
  const float* t2p = t2 + pstart + lg * 4;

  for (int g = 0; g < SUBLEN / 16; ++g) {
    bf16x8_t a0 = *reinterpret_cast<const bf16x8_t*>(aptr);
    bf16x8_t a1 = *reinterpret_cast<const bf16x8_t*>(aptr + 32);
    float4 t2v = *reinterpret_cast<const float4*>(t2p);
    f32x4_t c = {0.f, 0.f, 0.f, 0.f};
    c = __builtin_amdgcn_mfma_f32_16x16x32_bf16(a0, B0, c, 0, 0, 0);
    c = __builtin_amdgcn_mfma_f32_16x16x32_bf16(a1, B1, c, 0, 0, 0);
    float tmp0 = fmaf(-2.f, c[0], t2v.x);
    float tmp1 = fmaf(-2.f, c[1], t2v.y);
    float tmp2 = fmaf(-2.f, c[2], t2v.z);
    float tmp3 = fmaf(-2.f, c[3], t2v.w);
    #pragma unroll
    for (int r = 0; r < 4; ++r) {
      float tv = (r == 0) ? tmp0 : (r == 1) ? tmp1 : (r == 2) ? tmp2 : tmp3;
      if (tv < Ld[7]) {
        Ld[7] = tv;
        #pragma unroll
        for (int e = 7; e > 0; --e)
          if (Ld[e] < Ld[e - 1]) { float s = Ld[e]; Ld[e] = Ld[e - 1]; Ld[e - 1] = s; }
      }
    }
    aptr += 16 * D; t2p += 16;
  }

  // samp layout: [q][sub][lg*8 + e]  (= q*512 + (sub*4 + lg)*8 + e)
  float* outp = samp + (size_t)q * (NSUB * 32) + sub * 32 + lg * 8;
  *reinterpret_cast<float4*>(outp)     = make_float4(Ld[0], Ld[1], Ld[2], Ld[3]);
  *reinterpret_cast<float4*>(outp + 4) = make_float4(Ld[4], Ld[5], Ld[6], Ld[7]);
}

// ---- K2: one wave per query: merge 64 sorted-8 lists by 16 rounds of
//      wave-min-pop; theta = 16th popped value. Multi-pop on exact ties only
//      raises theta -> safe. ----
__global__ __launch_bounds__(256) void knn_theta(
    const float* __restrict__ samp, float* __restrict__ theta, int B)
{
  const int w = threadIdx.x >> 6, lane = threadIdx.x & 63;
  const int q = blockIdx.x * 4 + w;
  if (q >= B) return;

  const float* s = samp + (size_t)q * (NSUB * 32) + lane * 8;
  float4 v0 = *reinterpret_cast<const float4*>(s);
  float4 v1 = *reinterpret_cast<const float4*>(s + 4);
  float Ld[8] = {v0.x, v0.y, v0.z, v0.w, v1.x, v1.y, v1.z, v1.w};

  float th = INFINITY;
  for (int r = 0; r < K; ++r) {
    float bd = Ld[0];
    #pragma unroll
    for (int sdx = 0; sdx < 6; ++sdx) {
      float od = __shfl_xor(bd, 32 >> sdx);
      bd = fminf(bd, od);
    }
    if (Ld[0] == bd) {   // pop (all tying lanes pop; only loosens theta)
      #pragma unroll
      for (int e = 0; e < 7; ++e) Ld[e] = Ld[e + 1];
      Ld[7] = INFINITY;
    }
    th = bd;
  }
  if (lane == 0) theta[q] = th;
}

// ---- K3: main filter. grid (B/64, NCHUNK), 4 waves. Accepts go to per-query
//      LDS lists (block-scope LDS atomics only); block flush writes fixed
//      per-(q,chunk) slots. No global atomics anywhere. ----
__global__ __launch_bounds__(256) void knn_filter(
    const ushort_t* __restrict__ tb, const ushort_t* __restrict__ xb,
    const float* __restrict__ t2, const float* __restrict__ theta,
    int* __restrict__ cnts, int* __restrict__ cand, int N)
{
  __shared__ int cnt_l[64];
  __shared__ int list_l[64][SLOT];

  const int tid = threadIdx.x;
  const int w = tid >> 6, lane = tid & 63;
  const int lh = lane & 15, lg = lane >> 4;
  const int qloc = w * 16 + lh;             // block-local query 0..63
  const int qb = blockIdx.x, ch = blockIdx.y;
  const int q0 = qb * 64;
  const int q  = q0 + qloc;
  const int g0 = ch * CHUNKLEN;

  if (tid < 64) cnt_l[tid] = 0;
  __syncthreads();

  int navail = N - g0;
  const int ngroups = (navail <= 0) ? 0 : ((navail < CHUNKLEN ? navail : CHUNKLEN) >> 4);

  const ushort_t* xr = xb + (size_t)q * D + lg * 8;
  bf16x8_t B0 = *reinterpret_cast<const bf16x8_t*>(xr);
  bf16x8_t B1 = *reinterpret_cast<const bf16x8_t*>(xr + 32);
  const float th = theta[q];

  const ushort_t* aptr = tb + (size_t)g0 * D + lh * D + lg * 8;
  const float* t2p = t2 + g0 + lg * 4;
  int pbase = g0 + lg * 4;

  for (int g = 0; g < ngroups; ++g) {
    bf16x8_t a0 = *reinterpret_cast<const bf16x8_t*>(aptr);
    bf16x8_t a1 = *reinterpret_cast<const bf16x8_t*>(aptr + 32);
    float4 t2v = *reinterpret_cast<const float4*>(t2p);
    f32x4_t c = {0.f, 0.f, 0.f, 0.f};
    c = __builtin_amdgcn_mfma_f32_16x16x32_bf16(a0, B0, c, 0, 0, 0);
    c = __builtin_amdgcn_mfma_f32_16x16x32_bf16(a1, B1, c, 0, 0, 0);
    float tmp0 = fmaf(-2.f, c[0], t2v.x);
    float tmp1 = fmaf(-2.f, c[1], t2v.y);
    float tmp2 = fmaf(-2.f, c[2], t2v.z);
    float tmp3 = fmaf(-2.f, c[3], t2v.w);
    unsigned m = (tmp0 <= th ? 1u : 0u) | (tmp1 <= th ? 2u : 0u)
               | (tmp2 <= th ? 4u : 0u) | (tmp3 <= th ? 8u : 0u);
    if (m) {
      int n = __popc(m);
      int base = atomicAdd(&cnt_l[qloc], n);   // LDS atomic, block-scope
      while (m) {
        int r = __ffs(m) - 1; m &= m - 1;
        if (base < SLOT) list_l[qloc][base] = pbase + r;
        ++base;
      }
    }
    aptr += 16 * D; t2p += 16; pbase += 16;
  }

  __syncthreads();
  if (tid < 64) {
    int n = cnt_l[tid]; if (n > SLOT) n = SLOT;
    size_t o = (size_t)(q0 + tid) * NCHUNK + ch;
    cnts[o] = n;
    for (int j = 0; j < n; ++j) cand[o * SLOT + j] = list_l[tid][j];
  }
}

// ---- K4: exact fp32 rescore + (d2,idx)-lex top-16 + weighted vote.
//      4 queries/block, 1 wave each; scans fixed slots. ----
__global__ __launch_bounds__(256) void knn_vote(
    const float* __restrict__ x, const float* __restrict__ train,
    const float* __restrict__ t2, const int* __restrict__ labels,
    const int* __restrict__ cnts, const int* __restrict__ cand,
    float* __restrict__ out, int B, int N)
{
  const int w = threadIdx.x >> 6, lane = threadIdx.x & 63;
  const int q = blockIdx.x * 4 + w;
  if (q >= B) return;

  const float* xr = x + (size_t)q * D;
  float4 xv[16];
  #pragma unroll
  for (int i = 0; i < 16; ++i) xv[i] = *reinterpret_cast<const float4*>(xr + i * 4);
  float x2 = 0.f;
  #pragma unroll
  for (int i = 0; i < 16; ++i) {
    x2 = fmaf(xv[i].x, xv[i].x, x2); x2 = fmaf(xv[i].y, xv[i].y, x2);
    x2 = fmaf(xv[i].z, xv[i].z, x2); x2 = fmaf(xv[i].w, xv[i].w, x2);
  }

  float Ld[K]; int Li[K];
  #pragma unroll
  for (int e = 0; e < K; ++e) { Ld[e] = INFINITY; Li[e] = 0x7fffffff; }

  const int* qcnts = cnts + (size_t)q * NCHUNK;
  const int* qcand = cand + (size_t)q * NCHUNK * SLOT;
  for (int j = lane; j < NCHUNK * SLOT; j += 64) {
    int ch = j >> 5, pos = j & (SLOT - 1);
    if (pos < qcnts[ch]) {
      int idx = qcand[ch * SLOT + pos];
      const float* tr = train + (size_t)idx * D;
      float dot = 0.f;
      #pragma unroll
      for (int i = 0; i < 16; ++i) {
        float4 tv = *reinterpret_cast<const float4*>(tr + i * 4);
        dot = fmaf(xv[i].x, tv.x, dot); dot = fmaf(xv[i].y, tv.y, dot);
        dot = fmaf(xv[i].z, tv.z, dot); dot = fmaf(xv[i].w, tv.w, dot);
      }
      float d2 = fmaxf(x2 - 2.f * dot + t2[idx], 0.f);
      if (d2 < Ld[K - 1] || (d2 == Ld[K - 1] && idx < Li[K - 1])) {
        Ld[K - 1] = d2; Li[K - 1] = idx;
        #pragma unroll
        for (int e = K - 1; e > 0; --e) {
          bool sw = (Ld[e] < Ld[e - 1]) || (Ld[e] == Ld[e - 1] && Li[e] < Li[e - 1]);
          if (sw) {
            float td = Ld[e]; Ld[e] = Ld[e - 1]; Ld[e - 1] = td;
            int   ti = Li[e]; Li[e] = Li[e - 1]; Li[e - 1] = ti;
          }
        }
      }
    }
  }

  float accw[NCLS]; float acci[NCLS];
  #pragma unroll
  for (int c = 0; c < NCLS; ++c) { accw[c] = 0.f; acci[c] = 0.f; }
  int anyInf = 0;

  for (int r = 0; r < K; ++r) {
    float bd = Ld[0]; int bi = Li[0];
    #pragma unroll
    for (int s = 0; s < 6; ++s) {
      int off = 32 >> s;
      float od = __shfl_xor(bd, off);
      int   oi = __shfl_xor(bi, off);
      if (od < bd || (od == bd && oi < bi)) { bd = od; bi = oi; }
    }
    if (Ld[0] == bd && Li[0] == bi) {   // pop winner (idx unique -> one lane)
      #pragma unroll
      for (int e = 0; e < K - 1; ++e) { Ld[e] = Ld[e + 1]; Li[e] = Li[e + 1]; }
      Ld[K - 1] = INFINITY; Li[K - 1] = 0x7fffffff;
    }
    if (bd < INFINITY) {
      float dist = sqrtf(bd);
      int lab = labels[bi < N ? bi : 0];
      int isz = (dist == 0.f) ? 1 : 0;
      anyInf |= isz;
      float wgt = 1.f / dist;
      #pragma unroll
      for (int c = 0; c < NCLS; ++c) {
        accw[c] += (lab == c) ? wgt : 0.f;
        acci[c] += (lab == c && isz) ? 1.f : 0.f;
      }
    }
  }

  if (lane == 0) {
    float proba[NCLS]; float s = 0.f;
    #pragma unroll
    for (int c = 0; c < NCLS; ++c) { proba[c] = anyInf ? acci[c] : accw[c]; s += proba[c]; }
    if (s == 0.f) s = 1.f;
    #pragma unroll
    for (int c = 0; c < NCLS; ++c) proba[c] = proba[c] / s;
    int best = 0; float bv = proba[0];
    #pragma unroll
    for (int c = 1; c < NCLS; ++c) if (proba[c] > bv) { bv = proba[c]; best = c; }
    out[q] = (float)best;
    #pragma unroll
    for (int c = 0; c < NCLS; ++c) out[B + q * NCLS + c] = proba[c];
  }
}

extern "C" void kernel_launch(void* const* d_in, const int* in_sizes, int n_in,
                              void* d_out, int out_size, void* d_ws, size_t ws_size,
                              hipStream_t stream)
{
  const float* x      = (const float*)d_in[0];
  const float* train  = (const float*)d_in[1];
  const int*   labels = (const int*)d_in[2];
  float* out = (float*)d_out;

  const int B = in_sizes[0] / D;   // 1024
  const int N = in_sizes[2];       // 100000

  // workspace carve (16B-aligned)
  char* ws = (char*)d_ws;
  size_t off = 0;
  ushort_t* train_bf = (ushort_t*)(ws + off); off += (size_t)N * D * 2;            // 12.8 MB
  ushort_t* x_bf     = (ushort_t*)(ws + off); off += (size_t)B * D * 2;            // 128 KB
  float*    t2       = (float*)(ws + off);    off += (size_t)N * 4;                // 400 KB
  float*    samp     = (float*)(ws + off);    off += (size_t)B * NSUB * 32 * 4;    // 2 MB
  float*    theta    = (float*)(ws + off);    off += (size_t)B * 4;
  int*      cnts     = (int*)(ws + off);      off += (size_t)B * NCHUNK * 4;       // 400 KB
  int*      cand     = (int*)(ws + off);      off += (size_t)B * NCHUNK * SLOT * 4; // 12.9 MB

  cvt_train<<<(N * 4 + 255) / 256, 256, 0, stream>>>(train, train_bf, t2, N);
  cvt_x<<<(B * 4 + 255) / 256, 256, 0, stream>>>(x, x_bf, B);
  knn_sample<<<dim3(B / 64, NSUB), 256, 0, stream>>>(train_bf, x_bf, t2, samp);
  knn_theta<<<(B + 3) / 4, 256, 0, stream>>>(samp, theta, B);
  knn_filter<<<dim3(B / 64, NCHUNK), 256, 0, stream>>>(train_bf, x_bf, t2, theta, cnts, cand, N);
  knn_vote<<<(B + 3) / 4, 256, 0, stream>>>(x, train, t2, labels, cnts, cand, out, B, N);
}

// Round 6
// 230.141 us; speedup vs baseline: 2.1465x; 1.6107x over previous
//
#include <hip/hip_runtime.h>
#include <math.h>

// KNN (weights='distance'): B=1024 queries, N=100000 train, D=64, K=16, 10 classes.
// Pipeline: K0 fp32->bf16 + norms | K1 sample 8192 pts (per-lane top-8) |
// K2 wave-merge -> theta[q] (sample 16th smallest in t2-2c space) |
// K3 MFMA filter -> per-(q,chunk) fixed-slot lists via LDS (no global atomics) |
// K4 per-query block: compact slots -> exact fp32 rescore -> hierarchical
//    lex top-16 merge -> weighted vote.

constexpr int D        = 64;
constexpr int K        = 16;
constexpr int NCLS     = 10;
constexpr int CHUNKLEN = 1024;   // points per filter chunk (64 groups of 16)
constexpr int NCHUNK   = 98;     // 98*1024 = 100352 >= 100000
constexpr int NSUB     = 16;     // sample subchunks
constexpr int SUBLEN   = 512;    // sample points per subchunk (8192 total)
constexpr int SLOT     = 32;     // candidate slots per (query, chunk); avg fill ~2

typedef __attribute__((ext_vector_type(8))) short bf16x8_t;
typedef __attribute__((ext_vector_type(4))) float f32x4_t;
typedef unsigned short ushort_t;

__device__ __forceinline__ ushort_t f32_to_bf16_rne(float f) {
  unsigned int u = __float_as_uint(f);
  unsigned int r = u + 0x7FFFu + ((u >> 16) & 1u);
  return (ushort_t)(r >> 16);
}

// ---- K0a: train fp32 -> bf16, plus fp32 row norms. 4 threads/row. ----
__global__ __launch_bounds__(256) void cvt_train(
    const float* __restrict__ t, ushort_t* __restrict__ tb,
    float* __restrict__ t2, int N)
{
  int gid = blockIdx.x * 256 + threadIdx.x;
  int row = gid >> 2, qt = gid & 3;
  if (row >= N) return;
  const float* src = t + (size_t)row * D + qt * 16;
  ushort_t*    dst = tb + (size_t)row * D + qt * 16;
  float nrm = 0.f;
  #pragma unroll
  for (int i = 0; i < 4; ++i) {
    float4 v = *reinterpret_cast<const float4*>(src + i * 4);
    nrm = fmaf(v.x, v.x, nrm); nrm = fmaf(v.y, v.y, nrm);
    nrm = fmaf(v.z, v.z, nrm); nrm = fmaf(v.w, v.w, nrm);
    uint2 hh = make_uint2(
      (unsigned)f32_to_bf16_rne(v.x) | ((unsigned)f32_to_bf16_rne(v.y) << 16),
      (unsigned)f32_to_bf16_rne(v.z) | ((unsigned)f32_to_bf16_rne(v.w) << 16));
    *reinterpret_cast<uint2*>(dst + i * 4) = hh;
  }
  nrm += __shfl_xor(nrm, 1);
  nrm += __shfl_xor(nrm, 2);
  if (qt == 0) t2[row] = nrm;
}

// ---- K0b: x fp32 -> bf16. ----
__global__ __launch_bounds__(256) void cvt_x(
    const float* __restrict__ x, ushort_t* __restrict__ xb, int B)
{
  int gid = blockIdx.x * 256 + threadIdx.x;
  int row = gid >> 2, qt = gid & 3;
  if (row >= B) return;
  const float* src = x + (size_t)row * D + qt * 16;
  ushort_t*    dst = xb + (size_t)row * D + qt * 16;
  #pragma unroll
  for (int i = 0; i < 4; ++i) {
    float4 v = *reinterpret_cast<const float4*>(src + i * 4);
    uint2 hh = make_uint2(
      (unsigned)f32_to_bf16_rne(v.x) | ((unsigned)f32_to_bf16_rne(v.y) << 16),
      (unsigned)f32_to_bf16_rne(v.z) | ((unsigned)f32_to_bf16_rne(v.w) << 16));
    *reinterpret_cast<uint2*>(dst + i * 4) = hh;
  }
}

// ---- K1: sample pass. grid (B/64, NSUB). Lane keeps top-8 (sorted) of its
//      128 sample points in tmp = t2 - 2*dot space; writes raw 8 values. ----
__global__ __launch_bounds__(256) void knn_sample(
    const ushort_t* __restrict__ tb, const ushort_t* __restrict__ xb,
    const float* __restrict__ t2, float* __restrict__ samp)
{
  const int tid = threadIdx.x;
  const int w = tid >> 6, lane = tid & 63;
  const int lh = lane & 15, lg = lane >> 4;
  const int qb = blockIdx.x, sub = blockIdx.y;
  const int q = qb * 64 + w * 16 + lh;

  const ushort_t* xr = xb + (size_t)q * D + lg * 8;
  bf16x8_t B0 = *reinterpret_cast<const bf16x8_t*>(xr);
  bf16x8_t B1 = *reinterpret_cast<const bf16x8_t*>(xr + 32);

  float Ld[8];
  #pragma unroll
  for (int e = 0; e < 8; ++e) Ld[e] = INFINITY;

  const int pstart = sub * SUBLEN;
  const ushort_t* aptr = tb + (size_t)pstart * D + lh * D + lg * 8;
  const float* t2p = t2 + pstart + lg * 4;

  for (int g = 0; g < SUBLEN / 16; ++g) {
    bf16x8_t a0 = *reinterpret_cast<const bf16x8_t*>(aptr);
    bf16x8_t a1 = *reinterpret_cast<const bf16x8_t*>(aptr + 32);
    float4 t2v = *reinterpret_cast<const float4*>(t2p);
    f32x4_t c = {0.f, 0.f, 0.f, 0.f};
    c = __builtin_amdgcn_mfma_f32_16x16x32_bf16(a0, B0, c, 0, 0, 0);
    c = __builtin_amdgcn_mfma_f32_16x16x32_bf16(a1, B1, c, 0, 0, 0);
    float tmp0 = fmaf(-2.f, c[0], t2v.x);
    float tmp1 = fmaf(-2.f, c[1], t2v.y);
    float tmp2 = fmaf(-2.f, c[2], t2v.z);
    float tmp3 = fmaf(-2.f, c[3], t2v.w);
    #pragma unroll
    for (int r = 0; r < 4; ++r) {
      float tv = (r == 0) ? tmp0 : (r == 1) ? tmp1 : (r == 2) ? tmp2 : tmp3;
      if (tv < Ld[7]) {
        Ld[7] = tv;
        #pragma unroll
        for (int e = 7; e > 0; --e)
          if (Ld[e] < Ld[e - 1]) { float s = Ld[e]; Ld[e] = Ld[e - 1]; Ld[e - 1] = s; }
      }
    }
    aptr += 16 * D; t2p += 16;
  }

  float* outp = samp + (size_t)q * (NSUB * 32) + sub * 32 + lg * 8;
  *reinterpret_cast<float4*>(outp)     = make_float4(Ld[0], Ld[1], Ld[2], Ld[3]);
  *reinterpret_cast<float4*>(outp + 4) = make_float4(Ld[4], Ld[5], Ld[6], Ld[7]);
}

// ---- K2: one wave per query: merge 64 sorted-8 lists by 16 rounds of
//      wave-min-pop; theta = 16th popped value. ----
__global__ __launch_bounds__(256) void knn_theta(
    const float* __restrict__ samp, float* __restrict__ theta, int B)
{
  const int w = threadIdx.x >> 6, lane = threadIdx.x & 63;
  const int q = blockIdx.x * 4 + w;
  if (q >= B) return;

  const float* s = samp + (size_t)q * (NSUB * 32) + lane * 8;
  float4 v0 = *reinterpret_cast<const float4*>(s);
  float4 v1 = *reinterpret_cast<const float4*>(s + 4);
  float Ld[8] = {v0.x, v0.y, v0.z, v0.w, v1.x, v1.y, v1.z, v1.w};

  float th = INFINITY;
  for (int r = 0; r < K; ++r) {
    float bd = Ld[0];
    #pragma unroll
    for (int sdx = 0; sdx < 6; ++sdx) {
      float od = __shfl_xor(bd, 32 >> sdx);
      bd = fminf(bd, od);
    }
    if (Ld[0] == bd) {
      #pragma unroll
      for (int e = 0; e < 7; ++e) Ld[e] = Ld[e + 1];
      Ld[7] = INFINITY;
    }
    th = bd;
  }
  if (lane == 0) theta[q] = th;
}

// ---- K3: main filter. grid (B/64, NCHUNK), 4 waves. LDS lists, block flush
//      to fixed per-(q,chunk) slots. No global atomics. ----
__global__ __launch_bounds__(256) void knn_filter(
    const ushort_t* __restrict__ tb, const ushort_t* __restrict__ xb,
    const float* __restrict__ t2, const float* __restrict__ theta,
    int* __restrict__ cnts, int* __restrict__ cand, int N)
{
  __shared__ int cnt_l[64];
  __shared__ int list_l[64][SLOT];

  const int tid = threadIdx.x;
  const int w = tid >> 6, lane = tid & 63;
  const int lh = lane & 15, lg = lane >> 4;
  const int qloc = w * 16 + lh;
  const int qb = blockIdx.x, ch = blockIdx.y;
  const int q0 = qb * 64;
  const int q  = q0 + qloc;
  const int g0 = ch * CHUNKLEN;

  if (tid < 64) cnt_l[tid] = 0;
  __syncthreads();

  int navail = N - g0;
  const int ngroups = (navail <= 0) ? 0 : ((navail < CHUNKLEN ? navail : CHUNKLEN) >> 4);

  const ushort_t* xr = xb + (size_t)q * D + lg * 8;
  bf16x8_t B0 = *reinterpret_cast<const bf16x8_t*>(xr);
  bf16x8_t B1 = *reinterpret_cast<const bf16x8_t*>(xr + 32);
  const float th = theta[q];

  const ushort_t* aptr = tb + (size_t)g0 * D + lh * D + lg * 8;
  const float* t2p = t2 + g0 + lg * 4;
  int pbase = g0 + lg * 4;

  for (int g = 0; g < ngroups; ++g) {
    bf16x8_t a0 = *reinterpret_cast<const bf16x8_t*>(aptr);
    bf16x8_t a1 = *reinterpret_cast<const bf16x8_t*>(aptr + 32);
    float4 t2v = *reinterpret_cast<const float4*>(t2p);
    f32x4_t c = {0.f, 0.f, 0.f, 0.f};
    c = __builtin_amdgcn_mfma_f32_16x16x32_bf16(a0, B0, c, 0, 0, 0);
    c = __builtin_amdgcn_mfma_f32_16x16x32_bf16(a1, B1, c, 0, 0, 0);
    float tmp0 = fmaf(-2.f, c[0], t2v.x);
    float tmp1 = fmaf(-2.f, c[1], t2v.y);
    float tmp2 = fmaf(-2.f, c[2], t2v.z);
    float tmp3 = fmaf(-2.f, c[3], t2v.w);
    unsigned m = (tmp0 <= th ? 1u : 0u) | (tmp1 <= th ? 2u : 0u)
               | (tmp2 <= th ? 4u : 0u) | (tmp3 <= th ? 8u : 0u);
    if (m) {
      int n = __popc(m);
      int base = atomicAdd(&cnt_l[qloc], n);   // LDS atomic, block-scope
      while (m) {
        int r = __ffs(m) - 1; m &= m - 1;
        if (base < SLOT) list_l[qloc][base] = pbase + r;
        ++base;
      }
    }
    aptr += 16 * D; t2p += 16; pbase += 16;
  }

  __syncthreads();
  if (tid < 64) {
    int n = cnt_l[tid]; if (n > SLOT) n = SLOT;
    size_t o = (size_t)(q0 + tid) * NCHUNK + ch;
    cnts[o] = n;
    for (int j = 0; j < n; ++j) cand[o * SLOT + j] = list_l[tid][j];
  }
}

// ---- K4: one block per query. Compact slot lists in LDS, exact fp32
//      rescore, per-thread sorted-16, hierarchical lex-min merge, vote. ----
__global__ __launch_bounds__(256) void knn_vote(
    const float* __restrict__ x, const float* __restrict__ train,
    const float* __restrict__ t2, const int* __restrict__ labels,
    const int* __restrict__ cnts, const int* __restrict__ cand,
    float* __restrict__ out, int B, int N)
{
  __shared__ int   compact[NCHUNK * SLOT];   // 3136 ints = 12.5 KB
  __shared__ float xs[D];
  __shared__ float mergedD[4][K];
  __shared__ int   mergedI[4][K];
  __shared__ int   total_s;
  __shared__ float x2_s;

  const int tid = threadIdx.x;
  const int w = tid >> 6, lane = tid & 63;
  const int q = blockIdx.x;

  if (tid == 0) total_s = 0;
  if (tid < D) xs[tid] = x[(size_t)q * D + tid];
  __syncthreads();

  if (w == 0) {  // wave 0: x2 via shfl reduce
    float v = xs[lane];
    float s = v * v;
    #pragma unroll
    for (int o = 32; o > 0; o >>= 1) s += __shfl_xor(s, o);
    if (lane == 0) x2_s = s;
  }
  if (tid < NCHUNK) {  // compaction: thread-per-chunk
    int n = cnts[(size_t)q * NCHUNK + tid];
    int base = atomicAdd(&total_s, n);
    const int* src = cand + ((size_t)q * NCHUNK + tid) * SLOT;
    for (int j = 0; j < n; ++j) compact[base + j] = src[j];
  }
  __syncthreads();

  const int total = total_s;       // <= 3136 -> <= 13 entries/thread
  const float x2 = x2_s;

  // exact rescore + per-thread sorted-16 (lossless: 13 <= 16)
  float Ld[K]; int Li[K];
  #pragma unroll
  for (int e = 0; e < K; ++e) { Ld[e] = INFINITY; Li[e] = 0x7fffffff; }

  for (int j = tid; j < total; j += 256) {
    int idx = compact[j];
    const float* tr = train + (size_t)idx * D;
    float dot = 0.f;
    #pragma unroll
    for (int i = 0; i < 16; ++i) {
      float4 tv = *reinterpret_cast<const float4*>(tr + i * 4);
      dot = fmaf(xs[i * 4 + 0], tv.x, dot); dot = fmaf(xs[i * 4 + 1], tv.y, dot);
      dot = fmaf(xs[i * 4 + 2], tv.z, dot); dot = fmaf(xs[i * 4 + 3], tv.w, dot);
    }
    float d2v = fmaxf(x2 - 2.f * dot + t2[idx], 0.f);
    if (d2v < Ld[K - 1] || (d2v == Ld[K - 1] && idx < Li[K - 1])) {
      Ld[K - 1] = d2v; Li[K - 1] = idx;
      #pragma unroll
      for (int e = K - 1; e > 0; --e) {
        bool sw = (Ld[e] < Ld[e - 1]) || (Ld[e] == Ld[e - 1] && Li[e] < Li[e - 1]);
        if (sw) {
          float td = Ld[e]; Ld[e] = Ld[e - 1]; Ld[e - 1] = td;
          int   ti = Li[e]; Li[e] = Li[e - 1]; Li[e - 1] = ti;
        }
      }
    }
  }

  // per-wave 16-round lex-min pop-merge -> sorted-16 per wave in LDS
  for (int r = 0; r < K; ++r) {
    float bd = Ld[0]; int bi = Li[0];
    #pragma unroll
    for (int s = 0; s < 6; ++s) {
      int off = 32 >> s;
      float od = __shfl_xor(bd, off);
      int   oi = __shfl_xor(bi, off);
      if (od < bd || (od == bd && oi < bi)) { bd = od; bi = oi; }
    }
    if (Ld[0] == bd && Li[0] == bi) {   // idx unique -> exactly one popper
      #pragma unroll
      for (int e = 0; e < K - 1; ++e) { Ld[e] = Ld[e + 1]; Li[e] = Li[e + 1]; }
      Ld[K - 1] = INFINITY; Li[K - 1] = 0x7fffffff;
    }
    if (lane == 0) { mergedD[w][r] = bd; mergedI[w][r] = bi; }
  }
  __syncthreads();

  // wave 0: final 64-entry lex-min pop-merge; lane r keeps r-th neighbor
  if (w == 0) {
    float vd = mergedD[lane >> 4][lane & 15];
    int   vi = mergedI[lane >> 4][lane & 15];
    float myD = INFINITY; int myI = 0;
    for (int r = 0; r < K; ++r) {
      float bd = vd; int bi = vi;
      #pragma unroll
      for (int s = 0; s < 6; ++s) {
        int off = 32 >> s;
        float od = __shfl_xor(bd, off);
        int   oi = __shfl_xor(bi, off);
        if (od < bd || (od == bd && oi < bi)) { bd = od; bi = oi; }
      }
      if (vd == bd && vi == bi) { vd = INFINITY; vi = 0x7fffffff; }
      if (lane == r) { myD = bd; myI = bi; }
    }

    // votes: lanes 0..15 hold the 16 neighbors; parallel label loads
    int valid = (lane < K) && (myD < INFINITY) && (myI < N);
    float dist = sqrtf(fmaxf(myD, 0.f));
    int lab = valid ? labels[myI] : 0;
    int isz = (valid && dist == 0.f) ? 1 : 0;
    float wgt = 1.f / dist;

    float accw[NCLS]; float acci[NCLS]; int anyInf = 0;
    #pragma unroll
    for (int c = 0; c < NCLS; ++c) { accw[c] = 0.f; acci[c] = 0.f; }
    for (int r = 0; r < K; ++r) {
      int   vr = __shfl(valid, r);
      int   labr = __shfl(lab, r);
      float wgtr = __shfl(wgt, r);
      int   iszr = __shfl(isz, r);
      if (vr) {
        anyInf |= iszr;
        #pragma unroll
        for (int c = 0; c < NCLS; ++c) {
          accw[c] += (labr == c) ? wgtr : 0.f;
          acci[c] += (labr == c && iszr) ? 1.f : 0.f;
        }
      }
    }

    if (lane == 0) {
      float proba[NCLS]; float s = 0.f;
      #pragma unroll
      for (int c = 0; c < NCLS; ++c) { proba[c] = anyInf ? acci[c] : accw[c]; s += proba[c]; }
      if (s == 0.f) s = 1.f;
      #pragma unroll
      for (int c = 0; c < NCLS; ++c) proba[c] = proba[c] / s;
      int best = 0; float bv = proba[0];
      #pragma unroll
      for (int c = 1; c < NCLS; ++c) if (proba[c] > bv) { bv = proba[c]; best = c; }
      out[q] = (float)best;
      #pragma unroll
      for (int c = 0; c < NCLS; ++c) out[B + q * NCLS + c] = proba[c];
    }
  }
}

extern "C" void kernel_launch(void* const* d_in, const int* in_sizes, int n_in,
                              void* d_out, int out_size, void* d_ws, size_t ws_size,
                              hipStream_t stream)
{
  const float* x      = (const float*)d_in[0];
  const float* train  = (const float*)d_in[1];
  const int*   labels = (const int*)d_in[2];
  float* out = (float*)d_out;

  const int B = in_sizes[0] / D;   // 1024
  const int N = in_sizes[2];       // 100000

  // workspace carve (16B-aligned)
  char* ws = (char*)d_ws;
  size_t off = 0;
  ushort_t* train_bf = (ushort_t*)(ws + off); off += (size_t)N * D * 2;             // 12.8 MB
  ushort_t* x_bf     = (ushort_t*)(ws + off); off += (size_t)B * D * 2;             // 128 KB
  float*    t2       = (float*)(ws + off);    off += (size_t)N * 4;                 // 400 KB
  float*    samp     = (float*)(ws + off);    off += (size_t)B * NSUB * 32 * 4;     // 2 MB
  float*    theta    = (float*)(ws + off);    off += (size_t)B * 4;
  int*      cnts     = (int*)(ws + off);      off += (size_t)B * NCHUNK * 4;        // 400 KB
  int*      cand     = (int*)(ws + off);      off += (size_t)B * NCHUNK * SLOT * 4; // 12.9 MB

  cvt_train<<<(N * 4 + 255) / 256, 256, 0, stream>>>(train, train_bf, t2, N);
  cvt_x<<<(B * 4 + 255) / 256, 256, 0, stream>>>(x, x_bf, B);
  knn_sample<<<dim3(B / 64, NSUB), 256, 0, stream>>>(train_bf, x_bf, t2, samp);
  knn_theta<<<(B + 3) / 4, 256, 0, stream>>>(samp, theta, B);
  knn_filter<<<dim3(B / 64, NCHUNK), 256, 0, stream>>>(train_bf, x_bf, t2, theta, cnts, cand, N);
  knn_vote<<<B, 256, 0, stream>>>(x, train, t2, labels, cnts, cand, out, B, N);
}

// Round 7
// 131.713 us; speedup vs baseline: 3.7505x; 1.7473x over previous
//
#include <hip/hip_runtime.h>
#include <math.h>

// KNN (weights='distance'): B=1024 queries, N=100000 train, D=64, K=16, 10 classes.
// Pipeline: K0 fp32->bf16 + norms (padded rows -> t2=INF) | K1 sample 8192 pts |
// K2 merge -> theta[q] | K3 MFMA filter (wave = 64 queries x 256 points,
// depth-1 prefetch) -> per-(q,chunk) slots via LDS | K4 exact rescore + vote.

constexpr int D        = 64;
constexpr int K        = 16;
constexpr int NCLS     = 10;
constexpr int CHUNKLEN = 1024;   // points per filter chunk; wave owns 256 (16 groups)
constexpr int NCHUNK   = 98;     // 98*1024 = 100352 >= 100000
constexpr int NPAD     = NCHUNK * CHUNKLEN + 32;  // 100384 (prefetch overrun room)
constexpr int NSUB     = 32;     // sample subchunks
constexpr int SUBLEN   = 256;    // sample points per subchunk (8192 total)
constexpr int SLOT     = 32;     // candidate slots per (query, chunk)

typedef __attribute__((ext_vector_type(8))) short bf16x8_t;
typedef __attribute__((ext_vector_type(4))) float f32x4_t;
typedef unsigned short ushort_t;

__device__ __forceinline__ ushort_t f32_to_bf16_rne(float f) {
  unsigned int u = __float_as_uint(f);
  unsigned int r = u + 0x7FFFu + ((u >> 16) & 1u);
  return (ushort_t)(r >> 16);
}

// ---- K0a: train fp32 -> bf16 + fp32 norms; pad rows [N,NPAD): tb=0, t2=INF ----
__global__ __launch_bounds__(256) void cvt_train(
    const float* __restrict__ t, ushort_t* __restrict__ tb,
    float* __restrict__ t2, int N)
{
  int gid = blockIdx.x * 256 + threadIdx.x;
  int row = gid >> 2, qt = gid & 3;
  if (row >= NPAD) return;
  ushort_t* dst = tb + (size_t)row * D + qt * 16;
  if (row >= N) {
    uint2 z = make_uint2(0u, 0u);
    #pragma unroll
    for (int i = 0; i < 4; ++i) *reinterpret_cast<uint2*>(dst + i * 4) = z;
    if (qt == 0) t2[row] = INFINITY;
    return;
  }
  const float* src = t + (size_t)row * D + qt * 16;
  float nrm = 0.f;
  #pragma unroll
  for (int i = 0; i < 4; ++i) {
    float4 v = *reinterpret_cast<const float4*>(src + i * 4);
    nrm = fmaf(v.x, v.x, nrm); nrm = fmaf(v.y, v.y, nrm);
    nrm = fmaf(v.z, v.z, nrm); nrm = fmaf(v.w, v.w, nrm);
    uint2 hh = make_uint2(
      (unsigned)f32_to_bf16_rne(v.x) | ((unsigned)f32_to_bf16_rne(v.y) << 16),
      (unsigned)f32_to_bf16_rne(v.z) | ((unsigned)f32_to_bf16_rne(v.w) << 16));
    *reinterpret_cast<uint2*>(dst + i * 4) = hh;
  }
  nrm += __shfl_xor(nrm, 1);
  nrm += __shfl_xor(nrm, 2);
  if (qt == 0) t2[row] = nrm;
}

// ---- K0b: x fp32 -> bf16. ----
__global__ __launch_bounds__(256) void cvt_x(
    const float* __restrict__ x, ushort_t* __restrict__ xb, int B)
{
  int gid = blockIdx.x * 256 + threadIdx.x;
  int row = gid >> 2, qt = gid & 3;
  if (row >= B) return;
  const float* src = x + (size_t)row * D + qt * 16;
  ushort_t*    dst = xb + (size_t)row * D + qt * 16;
  #pragma unroll
  for (int i = 0; i < 4; ++i) {
    float4 v = *reinterpret_cast<const float4*>(src + i * 4);
    uint2 hh = make_uint2(
      (unsigned)f32_to_bf16_rne(v.x) | ((unsigned)f32_to_bf16_rne(v.y) << 16),
      (unsigned)f32_to_bf16_rne(v.z) | ((unsigned)f32_to_bf16_rne(v.w) << 16));
    *reinterpret_cast<uint2*>(dst + i * 4) = hh;
  }
}

// ---- K1: sample pass. grid (B/64, NSUB). Wave w: queries w*16..+16 over
//      SUBLEN=256 points (16 groups), depth-1 register prefetch.
//      Lane keeps sorted top-8 in tmp = t2 - 2*dot space. ----
__global__ __launch_bounds__(256) void knn_sample(
    const ushort_t* __restrict__ tb, const ushort_t* __restrict__ xb,
    const float* __restrict__ t2, float* __restrict__ samp)
{
  const int tid = threadIdx.x;
  const int w = tid >> 6, lane = tid & 63;
  const int lh = lane & 15, lg = lane >> 4;
  const int qb = blockIdx.x, sub = blockIdx.y;
  const int q = qb * 64 + w * 16 + lh;

  const ushort_t* xr = xb + (size_t)q * D + lg * 8;
  bf16x8_t B0 = *reinterpret_cast<const bf16x8_t*>(xr);
  bf16x8_t B1 = *reinterpret_cast<const bf16x8_t*>(xr + 32);

  float Ld[8];
  #pragma unroll
  for (int e = 0; e < 8; ++e) Ld[e] = INFINITY;

  const int pstart = sub * SUBLEN;
  const ushort_t* abase = tb + (size_t)pstart * D + lh * D + lg * 8;
  const float* tbase = t2 + pstart + lg * 4;

  // depth-1 prefetch (overrun group stays < N: 8192 + 272 << 100000)
  bf16x8_t a0c = *reinterpret_cast<const bf16x8_t*>(abase);
  bf16x8_t a1c = *reinterpret_cast<const bf16x8_t*>(abase + 32);
  float4   tvc = *reinterpret_cast<const float4*>(tbase);

  for (int g = 0; g < SUBLEN / 16; ++g) {
    const ushort_t* anx = abase + (size_t)(g + 1) * 16 * D;
    bf16x8_t a0n = *reinterpret_cast<const bf16x8_t*>(anx);
    bf16x8_t a1n = *reinterpret_cast<const bf16x8_t*>(anx + 32);
    float4   tvn = *reinterpret_cast<const float4*>(tbase + (g + 1) * 16);

    f32x4_t c = {0.f, 0.f, 0.f, 0.f};
    c = __builtin_amdgcn_mfma_f32_16x16x32_bf16(a0c, B0, c, 0, 0, 0);
    c = __builtin_amdgcn_mfma_f32_16x16x32_bf16(a1c, B1, c, 0, 0, 0);
    float tmp0 = fmaf(-2.f, c[0], tvc.x);
    float tmp1 = fmaf(-2.f, c[1], tvc.y);
    float tmp2 = fmaf(-2.f, c[2], tvc.z);
    float tmp3 = fmaf(-2.f, c[3], tvc.w);
    #pragma unroll
    for (int r = 0; r < 4; ++r) {
      float tv = (r == 0) ? tmp0 : (r == 1) ? tmp1 : (r == 2) ? tmp2 : tmp3;
      if (tv < Ld[7]) {
        Ld[7] = tv;
        #pragma unroll
        for (int e = 7; e > 0; --e)
          if (Ld[e] < Ld[e - 1]) { float s = Ld[e]; Ld[e] = Ld[e - 1]; Ld[e - 1] = s; }
      }
    }
    a0c = a0n; a1c = a1n; tvc = tvn;
  }

  float* outp = samp + (size_t)q * (NSUB * 32) + sub * 32 + lg * 8;
  *reinterpret_cast<float4*>(outp)     = make_float4(Ld[0], Ld[1], Ld[2], Ld[3]);
  *reinterpret_cast<float4*>(outp + 4) = make_float4(Ld[4], Ld[5], Ld[6], Ld[7]);
}

// ---- K2: one wave per query: 64 lanes x (two sorted-8 runs); 16 rounds of
//      wave-min two-headed pop; theta = 16th popped value (ties only loosen). ----
__global__ __launch_bounds__(256) void knn_theta(
    const float* __restrict__ samp, float* __restrict__ theta, int B)
{
  const int w = threadIdx.x >> 6, lane = threadIdx.x & 63;
  const int q = blockIdx.x * 4 + w;
  if (q >= B) return;

  const float* s = samp + (size_t)q * (NSUB * 32) + lane * 16;
  float4 p0 = *reinterpret_cast<const float4*>(s);
  float4 p1 = *reinterpret_cast<const float4*>(s + 4);
  float4 p2 = *reinterpret_cast<const float4*>(s + 8);
  float4 p3 = *reinterpret_cast<const float4*>(s + 12);
  float L0[8] = {p0.x, p0.y, p0.z, p0.w, p1.x, p1.y, p1.z, p1.w};
  float L1[8] = {p2.x, p2.y, p2.z, p2.w, p3.x, p3.y, p3.z, p3.w};

  float th = INFINITY;
  for (int r = 0; r < K; ++r) {
    float bd = fminf(L0[0], L1[0]);
    #pragma unroll
    for (int sdx = 0; sdx < 6; ++sdx) {
      float od = __shfl_xor(bd, 32 >> sdx);
      bd = fminf(bd, od);
    }
    if (L0[0] == bd) {
      #pragma unroll
      for (int e = 0; e < 7; ++e) L0[e] = L0[e + 1];
      L0[7] = INFINITY;
    }
    if (L1[0] == bd) {
      #pragma unroll
      for (int e = 0; e < 7; ++e) L1[e] = L1[e + 1];
      L1[7] = INFINITY;
    }
    th = bd;
  }
  if (lane == 0) theta[q] = th;
}

// ---- K3: main filter. grid (B/64, NCHUNK), 4 waves. Wave holds B-frags for
//      ALL 64 queries and owns a disjoint 256-point quarter (16 groups) with
//      depth-1 prefetch: 8 MFMA per A-load pair. LDS lists, block flush. ----
__global__ __launch_bounds__(256) void knn_filter(
    const ushort_t* __restrict__ tb, const ushort_t* __restrict__ xb,
    const float* __restrict__ t2, const float* __restrict__ theta,
    int* __restrict__ cnts, int* __restrict__ cand)
{
  __shared__ int cnt_l[64];
  __shared__ int list_l[64][SLOT];

  const int tid = threadIdx.x;
  const int w = tid >> 6, lane = tid & 63;
  const int lh = lane & 15, lg = lane >> 4;
  const int qb = blockIdx.x, ch = blockIdx.y;
  const int q0 = qb * 64;
  const int wp0 = ch * CHUNKLEN + w * (CHUNKLEN / 4);   // wave's point base

  if (tid < 64) cnt_l[tid] = 0;
  __syncthreads();

  // B fragments + thetas for all 4 query groups (static-indexed arrays)
  bf16x8_t Bq0[4], Bq1[4];
  float th[4];
  #pragma unroll
  for (int ct = 0; ct < 4; ++ct) {
    const ushort_t* xr = xb + (size_t)(q0 + ct * 16 + lh) * D + lg * 8;
    Bq0[ct] = *reinterpret_cast<const bf16x8_t*>(xr);
    Bq1[ct] = *reinterpret_cast<const bf16x8_t*>(xr + 32);
    th[ct] = theta[q0 + ct * 16 + lh];
  }

  const ushort_t* abase = tb + (size_t)wp0 * D + lh * D + lg * 8;
  const float* tbase = t2 + wp0 + lg * 4;

  // depth-1 prefetch; overrun group reads padded rows (t2=INF -> rejected)
  bf16x8_t a0c = *reinterpret_cast<const bf16x8_t*>(abase);
  bf16x8_t a1c = *reinterpret_cast<const bf16x8_t*>(abase + 32);
  float4   tvc = *reinterpret_cast<const float4*>(tbase);

  for (int g = 0; g < CHUNKLEN / 4 / 16; ++g) {   // 16 groups
    const ushort_t* anx = abase + (size_t)(g + 1) * 16 * D;
    bf16x8_t a0n = *reinterpret_cast<const bf16x8_t*>(anx);
    bf16x8_t a1n = *reinterpret_cast<const bf16x8_t*>(anx + 32);
    float4   tvn = *reinterpret_cast<const float4*>(tbase + (g + 1) * 16);

    const int pg = wp0 + g * 16 + lg * 4;   // point index of reg r=0
    #pragma unroll
    for (int ct = 0; ct < 4; ++ct) {
      f32x4_t c = {0.f, 0.f, 0.f, 0.f};
      c = __builtin_amdgcn_mfma_f32_16x16x32_bf16(a0c, Bq0[ct], c, 0, 0, 0);
      c = __builtin_amdgcn_mfma_f32_16x16x32_bf16(a1c, Bq1[ct], c, 0, 0, 0);
      float tmp0 = fmaf(-2.f, c[0], tvc.x);
      float tmp1 = fmaf(-2.f, c[1], tvc.y);
      float tmp2 = fmaf(-2.f, c[2], tvc.z);
      float tmp3 = fmaf(-2.f, c[3], tvc.w);
      unsigned m = (tmp0 <= th[ct] ? 1u : 0u) | (tmp1 <= th[ct] ? 2u : 0u)
                 | (tmp2 <= th[ct] ? 4u : 0u) | (tmp3 <= th[ct] ? 8u : 0u);
      if (m) {
        const int qloc = ct * 16 + lh;
        int n = __popc(m);
        int base = atomicAdd(&cnt_l[qloc], n);   // LDS atomic, block-scope
        while (m) {
          int r = __ffs(m) - 1; m &= m - 1;
          if (base < SLOT) list_l[qloc][base] = pg + r;
          ++base;
        }
      }
    }
    a0c = a0n; a1c = a1n; tvc = tvn;
  }

  __syncthreads();
  if (tid < 64) {
    int n = cnt_l[tid]; if (n > SLOT) n = SLOT;
    size_t o = (size_t)(q0 + tid) * NCHUNK + ch;
    cnts[o] = n;
    for (int j = 0; j < n; ++j) cand[o * SLOT + j] = list_l[tid][j];
  }
}

// ---- K4: one block per query. Compact slot lists in LDS, exact fp32
//      rescore, per-thread sorted-16, hierarchical lex-min merge, vote. ----
__global__ __launch_bounds__(256) void knn_vote(
    const float* __restrict__ x, const float* __restrict__ train,
    const float* __restrict__ t2, const int* __restrict__ labels,
    const int* __restrict__ cnts, const int* __restrict__ cand,
    float* __restrict__ out, int B, int N)
{
  __shared__ int   compact[NCHUNK * SLOT];   // 3136 ints = 12.5 KB
  __shared__ float xs[D];
  __shared__ float mergedD[4][K];
  __shared__ int   mergedI[4][K];
  __shared__ int   total_s;
  __shared__ float x2_s;

  const int tid = threadIdx.x;
  const int w = tid >> 6, lane = tid & 63;
  const int q = blockIdx.x;

  if (tid == 0) total_s = 0;
  if (tid < D) xs[tid] = x[(size_t)q * D + tid];
  __syncthreads();

  if (w == 0) {
    float v = xs[lane];
    float s = v * v;
    #pragma unroll
    for (int o = 32; o > 0; o >>= 1) s += __shfl_xor(s, o);
    if (lane == 0) x2_s = s;
  }
  if (tid < NCHUNK) {
    int n = cnts[(size_t)q * NCHUNK + tid];
    int base = atomicAdd(&total_s, n);
    const int* src = cand + ((size_t)q * NCHUNK + tid) * SLOT;
    for (int j = 0; j < n; ++j) compact[base + j] = src[j];
  }
  __syncthreads();

  const int total = total_s;
  const float x2 = x2_s;

  float Ld[K]; int Li[K];
  #pragma unroll
  for (int e = 0; e < K; ++e) { Ld[e] = INFINITY; Li[e] = 0x7fffffff; }

  for (int j = tid; j < total; j += 256) {
    int idx = compact[j];
    const float* tr = train + (size_t)idx * D;
    float dot = 0.f;
    #pragma unroll
    for (int i = 0; i < 16; ++i) {
      float4 tv = *reinterpret_cast<const float4*>(tr + i * 4);
      dot = fmaf(xs[i * 4 + 0], tv.x, dot); dot = fmaf(xs[i * 4 + 1], tv.y, dot);
      dot = fmaf(xs[i * 4 + 2], tv.z, dot); dot = fmaf(xs[i * 4 + 3], tv.w, dot);
    }
    float d2v = fmaxf(x2 - 2.f * dot + t2[idx], 0.f);
    if (d2v < Ld[K - 1] || (d2v == Ld[K - 1] && idx < Li[K - 1])) {
      Ld[K - 1] = d2v; Li[K - 1] = idx;
      #pragma unroll
      for (int e = K - 1; e > 0; --e) {
        bool sw = (Ld[e] < Ld[e - 1]) || (Ld[e] == Ld[e - 1] && Li[e] < Li[e - 1]);
        if (sw) {
          float td = Ld[e]; Ld[e] = Ld[e - 1]; Ld[e - 1] = td;
          int   ti = Li[e]; Li[e] = Li[e - 1]; Li[e - 1] = ti;
        }
      }
    }
  }

  for (int r = 0; r < K; ++r) {
    float bd = Ld[0]; int bi = Li[0];
    #pragma unroll
    for (int s = 0; s < 6; ++s) {
      int off = 32 >> s;
      float od = __shfl_xor(bd, off);
      int   oi = __shfl_xor(bi, off);
      if (od < bd || (od == bd && oi < bi)) { bd = od; bi = oi; }
    }
    if (Ld[0] == bd && Li[0] == bi) {
      #pragma unroll
      for (int e = 0; e < K - 1; ++e) { Ld[e] = Ld[e + 1]; Li[e] = Li[e + 1]; }
      Ld[K - 1] = INFINITY; Li[K - 1] = 0x7fffffff;
    }
    if (lane == 0) { mergedD[w][r] = bd; mergedI[w][r] = bi; }
  }
  __syncthreads();

  if (w == 0) {
    float vd = mergedD[lane >> 4][lane & 15];
    int   vi = mergedI[lane >> 4][lane & 15];
    float myD = INFINITY; int myI = 0;
    for (int r = 0; r < K; ++r) {
      float bd = vd; int bi = vi;
      #pragma unroll
      for (int s = 0; s < 6; ++s) {
        int off = 32 >> s;
        float od = __shfl_xor(bd, off);
        int   oi = __shfl_xor(bi, off);
        if (od < bd || (od == bd && oi < bi)) { bd = od; bi = oi; }
      }
      if (vd == bd && vi == bi) { vd = INFINITY; vi = 0x7fffffff; }
      if (lane == r) { myD = bd; myI = bi; }
    }

    int valid = (lane < K) && (myD < INFINITY) && (myI < N);
    float dist = sqrtf(fmaxf(myD, 0.f));
    int lab = valid ? labels[myI] : 0;
    int isz = (valid && dist == 0.f) ? 1 : 0;
    float wgt = 1.f / dist;

    float accw[NCLS]; float acci[NCLS]; int anyInf = 0;
    #pragma unroll
    for (int c = 0; c < NCLS; ++c) { accw[c] = 0.f; acci[c] = 0.f; }
    for (int r = 0; r < K; ++r) {
      int   vr = __shfl(valid, r);
      int   labr = __shfl(lab, r);
      float wgtr = __shfl(wgt, r);
      int   iszr = __shfl(isz, r);
      if (vr) {
        anyInf |= iszr;
        #pragma unroll
        for (int c = 0; c < NCLS; ++c) {
          accw[c] += (labr == c) ? wgtr : 0.f;
          acci[c] += (labr == c && iszr) ? 1.f : 0.f;
        }
      }
    }

    if (lane == 0) {
      float proba[NCLS]; float s = 0.f;
      #pragma unroll
      for (int c = 0; c < NCLS; ++c) { proba[c] = anyInf ? acci[c] : accw[c]; s += proba[c]; }
      if (s == 0.f) s = 1.f;
      #pragma unroll
      for (int c = 0; c < NCLS; ++c) proba[c] = proba[c] / s;
      int best = 0; float bv = proba[0];
      #pragma unroll
      for (int c = 1; c < NCLS; ++c) if (proba[c] > bv) { bv = proba[c]; best = c; }
      out[q] = (float)best;
      #pragma unroll
      for (int c = 0; c < NCLS; ++c) out[B + q * NCLS + c] = proba[c];
    }
  }
}

extern "C" void kernel_launch(void* const* d_in, const int* in_sizes, int n_in,
                              void* d_out, int out_size, void* d_ws, size_t ws_size,
                              hipStream_t stream)
{
  const float* x      = (const float*)d_in[0];
  const float* train  = (const float*)d_in[1];
  const int*   labels = (const int*)d_in[2];
  float* out = (float*)d_out;

  const int B = in_sizes[0] / D;   // 1024
  const int N = in_sizes[2];       // 100000

  // workspace carve (16B-aligned)
  char* ws = (char*)d_ws;
  size_t off = 0;
  ushort_t* train_bf = (ushort_t*)(ws + off); off += (size_t)NPAD * D * 2;          // 12.85 MB
  ushort_t* x_bf     = (ushort_t*)(ws + off); off += (size_t)B * D * 2;             // 128 KB
  float*    t2       = (float*)(ws + off);    off += (size_t)NPAD * 4;              // 402 KB
  float*    samp     = (float*)(ws + off);    off += (size_t)B * NSUB * 32 * 4;     // 4 MB
  float*    theta    = (float*)(ws + off);    off += (size_t)B * 4;
  int*      cnts     = (int*)(ws + off);      off += (size_t)B * NCHUNK * 4;        // 400 KB
  int*      cand     = (int*)(ws + off);      off += (size_t)B * NCHUNK * SLOT * 4; // 12.9 MB

  cvt_train<<<(NPAD * 4 + 255) / 256, 256, 0, stream>>>(train, train_bf, t2, N);
  cvt_x<<<(B * 4 + 255) / 256, 256, 0, stream>>>(x, x_bf, B);
  knn_sample<<<dim3(B / 64, NSUB), 256, 0, stream>>>(train_bf, x_bf, t2, samp);
  knn_theta<<<(B + 3) / 4, 256, 0, stream>>>(samp, theta, B);
  knn_filter<<<dim3(B / 64, NCHUNK), 256, 0, stream>>>(train_bf, x_bf, t2, theta, cnts, cand);
  knn_vote<<<B, 256, 0, stream>>>(x, train, t2, labels, cnts, cand, out, B, N);
}

// Round 8
// 114.321 us; speedup vs baseline: 4.3211x; 1.1521x over previous
//
#include <hip/hip_runtime.h>
#include <math.h>

// KNN (weights='distance'): B=1024 queries, N=100000 train, D=64, K=16, 10 classes.
// K0 fp32->bf16 + norms (pad t2=INF) | K1 sample 8192 pts | K2 theta[q] |
// K3 MFMA filter (depth-2 prefetch) -> per-(q,chunk) (idx,tmp) pair slots |
// K4 rank-by-count top-48 approx -> exact fp32 rescore of 48 -> top-16 -> vote.

constexpr int D        = 64;
constexpr int K        = 16;
constexpr int NCLS     = 10;
constexpr int CHUNKLEN = 1024;   // points per filter chunk; wave owns 256 (16 groups)
constexpr int NCHUNK   = 98;     // 98*1024 = 100352 >= 100000
constexpr int NPAD     = NCHUNK * CHUNKLEN + 32;  // 100384 (prefetch overrun room)
constexpr int NSUB     = 32;     // sample subchunks
constexpr int SUBLEN   = 256;    // sample points per subchunk (8192 total)
constexpr int SLOT     = 16;     // pair slots per (query, chunk); avg fill ~2
constexpr int MSEL     = 48;     // approx candidates kept for exact rescore

typedef __attribute__((ext_vector_type(8))) short bf16x8_t;
typedef __attribute__((ext_vector_type(4))) float f32x4_t;
typedef unsigned short ushort_t;

__device__ __forceinline__ ushort_t f32_to_bf16_rne(float f) {
  unsigned int u = __float_as_uint(f);
  unsigned int r = u + 0x7FFFu + ((u >> 16) & 1u);
  return (ushort_t)(r >> 16);
}

// ---- K0a: train fp32 -> bf16 + fp32 norms; pad rows [N,NPAD): tb=0, t2=INF ----
__global__ __launch_bounds__(256) void cvt_train(
    const float* __restrict__ t, ushort_t* __restrict__ tb,
    float* __restrict__ t2, int N)
{
  int gid = blockIdx.x * 256 + threadIdx.x;
  int row = gid >> 2, qt = gid & 3;
  if (row >= NPAD) return;
  ushort_t* dst = tb + (size_t)row * D + qt * 16;
  if (row >= N) {
    uint2 z = make_uint2(0u, 0u);
    #pragma unroll
    for (int i = 0; i < 4; ++i) *reinterpret_cast<uint2*>(dst + i * 4) = z;
    if (qt == 0) t2[row] = INFINITY;
    return;
  }
  const float* src = t + (size_t)row * D + qt * 16;
  float nrm = 0.f;
  #pragma unroll
  for (int i = 0; i < 4; ++i) {
    float4 v = *reinterpret_cast<const float4*>(src + i * 4);
    nrm = fmaf(v.x, v.x, nrm); nrm = fmaf(v.y, v.y, nrm);
    nrm = fmaf(v.z, v.z, nrm); nrm = fmaf(v.w, v.w, nrm);
    uint2 hh = make_uint2(
      (unsigned)f32_to_bf16_rne(v.x) | ((unsigned)f32_to_bf16_rne(v.y) << 16),
      (unsigned)f32_to_bf16_rne(v.z) | ((unsigned)f32_to_bf16_rne(v.w) << 16));
    *reinterpret_cast<uint2*>(dst + i * 4) = hh;
  }
  nrm += __shfl_xor(nrm, 1);
  nrm += __shfl_xor(nrm, 2);
  if (qt == 0) t2[row] = nrm;
}

// ---- K0b: x fp32 -> bf16. ----
__global__ __launch_bounds__(256) void cvt_x(
    const float* __restrict__ x, ushort_t* __restrict__ xb, int B)
{
  int gid = blockIdx.x * 256 + threadIdx.x;
  int row = gid >> 2, qt = gid & 3;
  if (row >= B) return;
  const float* src = x + (size_t)row * D + qt * 16;
  ushort_t*    dst = xb + (size_t)row * D + qt * 16;
  #pragma unroll
  for (int i = 0; i < 4; ++i) {
    float4 v = *reinterpret_cast<const float4*>(src + i * 4);
    uint2 hh = make_uint2(
      (unsigned)f32_to_bf16_rne(v.x) | ((unsigned)f32_to_bf16_rne(v.y) << 16),
      (unsigned)f32_to_bf16_rne(v.z) | ((unsigned)f32_to_bf16_rne(v.w) << 16));
    *reinterpret_cast<uint2*>(dst + i * 4) = hh;
  }
}

// ---- K1: sample pass. grid (B/64, NSUB). Lane keeps sorted top-8 of its
//      points in tmp = t2 - 2*dot space; depth-1 prefetch. ----
__global__ __launch_bounds__(256) void knn_sample(
    const ushort_t* __restrict__ tb, const ushort_t* __restrict__ xb,
    const float* __restrict__ t2, float* __restrict__ samp)
{
  const int tid = threadIdx.x;
  const int w = tid >> 6, lane = tid & 63;
  const int lh = lane & 15, lg = lane >> 4;
  const int qb = blockIdx.x, sub = blockIdx.y;
  const int q = qb * 64 + w * 16 + lh;

  const ushort_t* xr = xb + (size_t)q * D + lg * 8;
  bf16x8_t B0 = *reinterpret_cast<const bf16x8_t*>(xr);
  bf16x8_t B1 = *reinterpret_cast<const bf16x8_t*>(xr + 32);

  float Ld[8];
  #pragma unroll
  for (int e = 0; e < 8; ++e) Ld[e] = INFINITY;

  const int pstart = sub * SUBLEN;
  const ushort_t* abase = tb + (size_t)pstart * D + lh * D + lg * 8;
  const float* tbase = t2 + pstart + lg * 4;

  bf16x8_t a0c = *reinterpret_cast<const bf16x8_t*>(abase);
  bf16x8_t a1c = *reinterpret_cast<const bf16x8_t*>(abase + 32);
  float4   tvc = *reinterpret_cast<const float4*>(tbase);

  for (int g = 0; g < SUBLEN / 16; ++g) {
    const ushort_t* anx = abase + (size_t)(g + 1) * 16 * D;
    bf16x8_t a0n = *reinterpret_cast<const bf16x8_t*>(anx);
    bf16x8_t a1n = *reinterpret_cast<const bf16x8_t*>(anx + 32);
    float4   tvn = *reinterpret_cast<const float4*>(tbase + (g + 1) * 16);

    f32x4_t c = {0.f, 0.f, 0.f, 0.f};
    c = __builtin_amdgcn_mfma_f32_16x16x32_bf16(a0c, B0, c, 0, 0, 0);
    c = __builtin_amdgcn_mfma_f32_16x16x32_bf16(a1c, B1, c, 0, 0, 0);
    float tmp0 = fmaf(-2.f, c[0], tvc.x);
    float tmp1 = fmaf(-2.f, c[1], tvc.y);
    float tmp2 = fmaf(-2.f, c[2], tvc.z);
    float tmp3 = fmaf(-2.f, c[3], tvc.w);
    #pragma unroll
    for (int r = 0; r < 4; ++r) {
      float tv = (r == 0) ? tmp0 : (r == 1) ? tmp1 : (r == 2) ? tmp2 : tmp3;
      if (tv < Ld[7]) {
        Ld[7] = tv;
        #pragma unroll
        for (int e = 7; e > 0; --e)
          if (Ld[e] < Ld[e - 1]) { float s = Ld[e]; Ld[e] = Ld[e - 1]; Ld[e - 1] = s; }
      }
    }
    a0c = a0n; a1c = a1n; tvc = tvn;
  }

  float* outp = samp + (size_t)q * (NSUB * 32) + sub * 32 + lg * 8;
  *reinterpret_cast<float4*>(outp)     = make_float4(Ld[0], Ld[1], Ld[2], Ld[3]);
  *reinterpret_cast<float4*>(outp + 4) = make_float4(Ld[4], Ld[5], Ld[6], Ld[7]);
}

// ---- K2: one wave per query: 64 lanes x two sorted-8 runs; 16 rounds of
//      wave-min pop; theta = 16th popped (ties only loosen -> safe). ----
__global__ __launch_bounds__(256) void knn_theta(
    const float* __restrict__ samp, float* __restrict__ theta, int B)
{
  const int w = threadIdx.x >> 6, lane = threadIdx.x & 63;
  const int q = blockIdx.x * 4 + w;
  if (q >= B) return;

  const float* s = samp + (size_t)q * (NSUB * 32) + lane * 16;
  float4 p0 = *reinterpret_cast<const float4*>(s);
  float4 p1 = *reinterpret_cast<const float4*>(s + 4);
  float4 p2 = *reinterpret_cast<const float4*>(s + 8);
  float4 p3 = *reinterpret_cast<const float4*>(s + 12);
  float L0[8] = {p0.x, p0.y, p0.z, p0.w, p1.x, p1.y, p1.z, p1.w};
  float L1[8] = {p2.x, p2.y, p2.z, p2.w, p3.x, p3.y, p3.z, p3.w};

  float th = INFINITY;
  for (int r = 0; r < K; ++r) {
    float bd = fminf(L0[0], L1[0]);
    #pragma unroll
    for (int sdx = 0; sdx < 6; ++sdx) {
      float od = __shfl_xor(bd, 32 >> sdx);
      bd = fminf(bd, od);
    }
    if (L0[0] == bd) {
      #pragma unroll
      for (int e = 0; e < 7; ++e) L0[e] = L0[e + 1];
      L0[7] = INFINITY;
    }
    if (L1[0] == bd) {
      #pragma unroll
      for (int e = 0; e < 7; ++e) L1[e] = L1[e + 1];
      L1[7] = INFINITY;
    }
    th = bd;
  }
  if (lane == 0) theta[q] = th;
}

// ---- K3: main filter. grid (B/64, NCHUNK), 4 waves. Wave holds B-frags for
//      all 64 queries, owns 256 points; unroll-2 + depth-2 prefetch.
//      Accepts -> LDS (idx,tmp) pairs; block flush to fixed slots. ----
__global__ __launch_bounds__(256) void knn_filter(
    const ushort_t* __restrict__ tb, const ushort_t* __restrict__ xb,
    const float* __restrict__ t2, const float* __restrict__ theta,
    int* __restrict__ cnts, int2* __restrict__ cand2)
{
  __shared__ int  cnt_l[64];
  __shared__ int2 list_p[64][SLOT];   // 8 KB

  const int tid = threadIdx.x;
  const int w = tid >> 6, lane = tid & 63;
  const int lh = lane & 15, lg = lane >> 4;
  const int qb = blockIdx.x, ch = blockIdx.y;
  const int q0 = qb * 64;
  const int wp0 = ch * CHUNKLEN + w * (CHUNKLEN / 4);

  if (tid < 64) cnt_l[tid] = 0;
  __syncthreads();

  bf16x8_t Bq0[4], Bq1[4];
  float th[4];
  #pragma unroll
  for (int ct = 0; ct < 4; ++ct) {
    const ushort_t* xr = xb + (size_t)(q0 + ct * 16 + lh) * D + lg * 8;
    Bq0[ct] = *reinterpret_cast<const bf16x8_t*>(xr);
    Bq1[ct] = *reinterpret_cast<const bf16x8_t*>(xr + 32);
    th[ct] = theta[q0 + ct * 16 + lh];
  }

  const ushort_t* abase = tb + (size_t)wp0 * D + lh * D + lg * 8;
  const float* tbase = t2 + wp0 + lg * 4;

  // two groups in flight + two prefetched (all static-named registers)
  bf16x8_t cA0 = *reinterpret_cast<const bf16x8_t*>(abase);
  bf16x8_t cA1 = *reinterpret_cast<const bf16x8_t*>(abase + 32);
  float4   cTA = *reinterpret_cast<const float4*>(tbase);
  bf16x8_t cB0 = *reinterpret_cast<const bf16x8_t*>(abase + (size_t)16 * D);
  bf16x8_t cB1 = *reinterpret_cast<const bf16x8_t*>(abase + (size_t)16 * D + 32);
  float4   cTB = *reinterpret_cast<const float4*>(tbase + 16);

  #define PROCESS(A0_, A1_, TV_, GIDX_)                                          \
    {                                                                            \
      const int pg = wp0 + (GIDX_) * 16 + lg * 4;                                \
      _Pragma("unroll")                                                          \
      for (int ct = 0; ct < 4; ++ct) {                                           \
        f32x4_t c = {0.f, 0.f, 0.f, 0.f};                                        \
        c = __builtin_amdgcn_mfma_f32_16x16x32_bf16(A0_, Bq0[ct], c, 0, 0, 0);   \
        c = __builtin_amdgcn_mfma_f32_16x16x32_bf16(A1_, Bq1[ct], c, 0, 0, 0);   \
        float tmp0 = fmaf(-2.f, c[0], TV_.x);                                    \
        float tmp1 = fmaf(-2.f, c[1], TV_.y);                                    \
        float tmp2 = fmaf(-2.f, c[2], TV_.z);                                    \
        float tmp3 = fmaf(-2.f, c[3], TV_.w);                                    \
        unsigned m = (tmp0 <= th[ct] ? 1u : 0u) | (tmp1 <= th[ct] ? 2u : 0u)     \
                   | (tmp2 <= th[ct] ? 4u : 0u) | (tmp3 <= th[ct] ? 8u : 0u);    \
        if (m) {                                                                 \
          const int qloc = ct * 16 + lh;                                         \
          int n = __popc(m);                                                     \
          int base = atomicAdd(&cnt_l[qloc], n);                                 \
          while (m) {                                                            \
            int r = __ffs(m) - 1; m &= m - 1;                                    \
            float ts = (r == 0) ? tmp0 : (r == 1) ? tmp1 : (r == 2) ? tmp2 : tmp3;\
            if (base < SLOT)                                                     \
              list_p[qloc][base] = make_int2(pg + r, __float_as_int(ts));        \
            ++base;                                                              \
          }                                                                      \
        }                                                                        \
      }                                                                          \
    }

  for (int g = 0; g < 8; ++g) {   // 8 iters x 2 groups = 16 groups
    const ushort_t* an = abase + (size_t)(2 * g + 2) * 16 * D;
    bf16x8_t nA0 = *reinterpret_cast<const bf16x8_t*>(an);
    bf16x8_t nA1 = *reinterpret_cast<const bf16x8_t*>(an + 32);
    float4   nTA = *reinterpret_cast<const float4*>(tbase + (2 * g + 2) * 16);
    bf16x8_t nB0 = *reinterpret_cast<const bf16x8_t*>(an + (size_t)16 * D);
    bf16x8_t nB1 = *reinterpret_cast<const bf16x8_t*>(an + (size_t)16 * D + 32);
    float4   nTB = *reinterpret_cast<const float4*>(tbase + (2 * g + 3) * 16);

    PROCESS(cA0, cA1, cTA, 2 * g);
    PROCESS(cB0, cB1, cTB, 2 * g + 1);

    cA0 = nA0; cA1 = nA1; cTA = nTA;
    cB0 = nB0; cB1 = nB1; cTB = nTB;
  }
  #undef PROCESS

  __syncthreads();
  if (tid < 64) {
    int n = cnt_l[tid]; if (n > SLOT) n = SLOT;
    size_t o = (size_t)(q0 + tid) * NCHUNK + ch;
    cnts[o] = n;
    for (int j = 0; j < n; ++j) cand2[o * SLOT + j] = list_p[tid][j];
  }
}

// ---- K4: one block per query. Compact (idx,tmp) pairs in LDS, rank-by-count
//      -> top-MSEL approx, exact fp32 rescore of MSEL, top-16 pop, vote. ----
__global__ __launch_bounds__(256) void knn_vote(
    const float* __restrict__ x, const float* __restrict__ train,
    const float* __restrict__ t2, const int* __restrict__ labels,
    const int* __restrict__ cnts, const int2* __restrict__ cand2,
    float* __restrict__ out, int B, int N)
{
  __shared__ int2  cpair[NCHUNK * SLOT];   // 1568 pairs = 12.25 KB
  __shared__ float sortd[MSEL];
  __shared__ int   sorti[MSEL];
  __shared__ float xs[D];
  __shared__ int   total_s;
  __shared__ float x2_s;

  const int tid = threadIdx.x;
  const int w = tid >> 6, lane = tid & 63;
  const int q = blockIdx.x;

  if (tid == 0) total_s = 0;
  if (tid < D) xs[tid] = x[(size_t)q * D + tid];
  if (tid < MSEL) { sortd[tid] = INFINITY; sorti[tid] = 0x7fffffff; }
  __syncthreads();

  if (w == 0) {   // x2 via wave0 shfl reduce (xs visible after barrier)
    float v = xs[lane];
    float s = v * v;
    #pragma unroll
    for (int o = 32; o > 0; o >>= 1) s += __shfl_xor(s, o);
    if (lane == 0) x2_s = s;
  }
  if (tid < NCHUNK) {   // compaction: thread-per-chunk, LDS atomic base
    int n = cnts[(size_t)q * NCHUNK + tid];
    int base = atomicAdd(&total_s, n);
    const int2* src = cand2 + ((size_t)q * NCHUNK + tid) * SLOT;
    for (int j = 0; j < n; ++j) cpair[base + j] = src[j];
  }
  __syncthreads();

  const int total = total_s;     // <= 1568; typically ~195
  const float x2 = x2_s;

  // rank-by-count over (tmp, idx) lex order (idx unique -> total order);
  // all threads stream the same LDS addresses -> broadcast reads.
  for (int j = tid; j < total; j += 256) {
    int2 mine = cpair[j];
    float md = __int_as_float(mine.y);
    int   mi = mine.x;
    int rank = 0;
    for (int k = 0; k < total; ++k) {
      int2 o = cpair[k];
      float od = __int_as_float(o.y);
      rank += (od < md || (od == md && o.x < mi)) ? 1 : 0;
    }
    if (rank < MSEL) { sortd[rank] = md; sorti[rank] = mi; }
  }
  __syncthreads();

  // exact fp32 rescore of the MSEL approx-best (tid<MSEL all in wave 0..)
  if (tid < MSEL) {
    int idx = sorti[tid];
    float d2v = INFINITY;
    if (idx != 0x7fffffff) {
      const float* tr = train + (size_t)idx * D;
      float dot = 0.f;
      #pragma unroll
      for (int i = 0; i < 16; ++i) {
        float4 tv = *reinterpret_cast<const float4*>(tr + i * 4);
        dot = fmaf(xs[i * 4 + 0], tv.x, dot); dot = fmaf(xs[i * 4 + 1], tv.y, dot);
        dot = fmaf(xs[i * 4 + 2], tv.z, dot); dot = fmaf(xs[i * 4 + 3], tv.w, dot);
      }
      d2v = fmaxf(x2 - 2.f * dot + t2[idx], 0.f);
    }
    sortd[tid] = d2v;   // overwrite approx with exact
  }
  __syncthreads();

  if (w == 0) {
    float vd = (lane < MSEL) ? sortd[lane] : INFINITY;
    int   vi = (lane < MSEL) ? sorti[lane] : 0x7fffffff;
    float myD = INFINITY; int myI = 0;
    for (int r = 0; r < K; ++r) {      // exact lex top-16 extraction
      float bd = vd; int bi = vi;
      #pragma unroll
      for (int s = 0; s < 6; ++s) {
        int off = 32 >> s;
        float od = __shfl_xor(bd, off);
        int   oi = __shfl_xor(bi, off);
        if (od < bd || (od == bd && oi < bi)) { bd = od; bi = oi; }
      }
      if (vd == bd && vi == bi) { vd = INFINITY; vi = 0x7fffffff; }
      if (lane == r) { myD = bd; myI = bi; }
    }

    int valid = (lane < K) && (myD < INFINITY) && (myI < N);
    float dist = sqrtf(fmaxf(myD, 0.f));
    int lab = labels[(valid && myI < N) ? myI : 0];
    int isz = (valid && dist == 0.f) ? 1 : 0;
    float wgt = 1.f / dist;

    float accw[NCLS]; float acci[NCLS]; int anyInf = 0;
    #pragma unroll
    for (int c = 0; c < NCLS; ++c) { accw[c] = 0.f; acci[c] = 0.f; }
    for (int r = 0; r < K; ++r) {
      int   vr   = __shfl(valid, r);
      int   labr = __shfl(lab, r);
      float wgtr = __shfl(wgt, r);
      int   iszr = __shfl(isz, r);
      if (vr) {
        anyInf |= iszr;
        #pragma unroll
        for (int c = 0; c < NCLS; ++c) {
          accw[c] += (labr == c) ? wgtr : 0.f;
          acci[c] += (labr == c && iszr) ? 1.f : 0.f;
        }
      }
    }

    if (lane == 0) {
      float proba[NCLS]; float s = 0.f;
      #pragma unroll
      for (int c = 0; c < NCLS; ++c) { proba[c] = anyInf ? acci[c] : accw[c]; s += proba[c]; }
      if (s == 0.f) s = 1.f;
      #pragma unroll
      for (int c = 0; c < NCLS; ++c) proba[c] = proba[c] / s;
      int best = 0; float bv = proba[0];
      #pragma unroll
      for (int c = 1; c < NCLS; ++c) if (proba[c] > bv) { bv = proba[c]; best = c; }
      out[q] = (float)best;
      #pragma unroll
      for (int c = 0; c < NCLS; ++c) out[B + q * NCLS + c] = proba[c];
    }
  }
}

extern "C" void kernel_launch(void* const* d_in, const int* in_sizes, int n_in,
                              void* d_out, int out_size, void* d_ws, size_t ws_size,
                              hipStream_t stream)
{
  const float* x      = (const float*)d_in[0];
  const float* train  = (const float*)d_in[1];
  const int*   labels = (const int*)d_in[2];
  float* out = (float*)d_out;

  const int B = in_sizes[0] / D;   // 1024
  const int N = in_sizes[2];       // 100000

  // workspace carve (16B-aligned), ~30.6 MB total
  char* ws = (char*)d_ws;
  size_t off = 0;
  ushort_t* train_bf = (ushort_t*)(ws + off); off += (size_t)NPAD * D * 2;           // 12.85 MB
  ushort_t* x_bf     = (ushort_t*)(ws + off); off += (size_t)B * D * 2;              // 128 KB
  float*    t2       = (float*)(ws + off);    off += (size_t)NPAD * 4;               // 402 KB
  float*    samp     = (float*)(ws + off);    off += (size_t)B * NSUB * 32 * 4;      // 4 MB
  float*    theta    = (float*)(ws + off);    off += (size_t)B * 4;
  int*      cnts     = (int*)(ws + off);      off += (size_t)B * NCHUNK * 4;         // 400 KB
  int2*     cand2    = (int2*)(ws + off);     off += (size_t)B * NCHUNK * SLOT * 8;  // 12.85 MB

  cvt_train<<<(NPAD * 4 + 255) / 256, 256, 0, stream>>>(train, train_bf, t2, N);
  cvt_x<<<(B * 4 + 255) / 256, 256, 0, stream>>>(x, x_bf, B);
  knn_sample<<<dim3(B / 64, NSUB), 256, 0, stream>>>(train_bf, x_bf, t2, samp);
  knn_theta<<<(B + 3) / 4, 256, 0, stream>>>(samp, theta, B);
  knn_filter<<<dim3(B / 64, NCHUNK), 256, 0, stream>>>(train_bf, x_bf, t2, theta, cnts, cand2);
  knn_vote<<<B, 256, 0, stream>>>(x, train, t2, labels, cnts, cand2, out, B, N);
}